// Round 14
// baseline (1272.115 us; speedup 1.0000x reference)
//
#include <hip/hip_runtime.h>
#include <hip/hip_bf16.h>

#define TOK   8192      // B*S
#define HD    1024      // H
#define FD    4096      // F
#define NE    8         // E
#define TOPK  2
#define NPAIR (TOK*TOPK)   // 16384, fixed
#define PADR  128          // row padding for tile overrun
#define BM    128
#define BN    256
#define BK    32
#define TMAX  (NPAIR/BM + NE)   // 136 grid rows; nwg stays %8==0

typedef short bf16x8 __attribute__((ext_vector_type(8)));
typedef float f32x4  __attribute__((ext_vector_type(4)));

__device__ inline unsigned short f2bf(float f) {
    unsigned u = __float_as_uint(f);
    unsigned r = (u + 0x7fffu + ((u >> 16) & 1u)) >> 16;
    return (unsigned short)r;
}

// ---------------- transpose + fp32->bf16 convert: in [E][R][C] -> out [E][C][R]
template<int R, int C>
__global__ __launch_bounds__(256) void transpose_cvt_kernel(
    const float* __restrict__ in, short* __restrict__ out)
{
    __shared__ float tile[64][65];
    const int tid = threadIdx.x;
    const int c0 = blockIdx.x * 64, r0 = blockIdx.y * 64, e = blockIdx.z;
    #pragma unroll
    for (int i = 0; i < 4; ++i) {
        int idx = i * 1024 + tid * 4;
        int rr = idx >> 6, cc = idx & 63;
        float4 v = *(const float4*)&in[((size_t)e * R + r0 + rr) * C + c0 + cc];
        tile[rr][cc] = v.x; tile[rr][cc + 1] = v.y;
        tile[rr][cc + 2] = v.z; tile[rr][cc + 3] = v.w;
    }
    __syncthreads();
    #pragma unroll
    for (int i = 0; i < 8; ++i) {
        int idx = i * 256 + tid;
        int cc = idx >> 5, rp = idx & 31;
        unsigned lo = f2bf(tile[rp * 2][cc]);
        unsigned hi = f2bf(tile[rp * 2 + 1][cc]);
        unsigned w = lo | (hi << 16);
        *(unsigned*)&out[((size_t)e * C + c0 + cc) * R + r0 + rp * 2] = w;
    }
}

// ---------------- gating: fp64 LN + logits + softmax + top-2 (one wave per token)
__global__ __launch_bounds__(256) void gating_kernel(
    const float* __restrict__ x, const float* __restrict__ gn_g, const float* __restrict__ gn_b,
    const float* __restrict__ gate_w, const float* __restrict__ gate_b,
    int* __restrict__ topk_i, float* __restrict__ topk_w, int* __restrict__ counts)
{
    const int wv = threadIdx.x >> 6, lane = threadIdx.x & 63;
    const int t = blockIdx.x * 4 + wv;
    const float* xr = x + (size_t)t * HD;

    double xs[16];
    #pragma unroll
    for (int i = 0; i < 16; ++i) xs[i] = (double)xr[i * 64 + lane];
    double s = 0.0;
    #pragma unroll
    for (int i = 0; i < 16; ++i) s += xs[i];
    #pragma unroll
    for (int o = 32; o > 0; o >>= 1) s += __shfl_xor(s, o, 64);
    double mean = s * (1.0 / HD);
    double ss = 0.0;
    #pragma unroll
    for (int i = 0; i < 16; ++i) { double d = xs[i] - mean; ss += d * d; }
    #pragma unroll
    for (int o = 32; o > 0; o >>= 1) ss += __shfl_xor(ss, o, 64);
    double inv = 1.0 / sqrt(ss * (1.0 / HD) + 1e-5);

    double ac[NE];
    #pragma unroll
    for (int e = 0; e < NE; ++e) ac[e] = 0.0;
    #pragma unroll
    for (int i = 0; i < 16; ++i) {
        int h = i * 64 + lane;
        double ln = (xs[i] - mean) * inv * (double)gn_g[h] + (double)gn_b[h];
        #pragma unroll
        for (int e = 0; e < NE; ++e) ac[e] += ln * (double)gate_w[h * NE + e];
    }
    #pragma unroll
    for (int e = 0; e < NE; ++e) {
        #pragma unroll
        for (int o = 32; o > 0; o >>= 1) ac[e] += __shfl_xor(ac[e], o, 64);
    }
    if (lane == 0) {
        double lg[NE], p[NE];
        double mx = -1e300;
        #pragma unroll
        for (int e = 0; e < NE; ++e) { lg[e] = ac[e] + (double)gate_b[e]; mx = lg[e] > mx ? lg[e] : mx; }
        double ps = 0.0;
        #pragma unroll
        for (int e = 0; e < NE; ++e) { p[e] = exp(lg[e] - mx); ps += p[e]; }
        #pragma unroll
        for (int e = 0; e < NE; ++e) p[e] /= ps;
        int i0 = 0;
        for (int e = 1; e < NE; ++e) if (p[e] > p[i0]) i0 = e;   // strict > keeps first (jax tie rule)
        int i1 = (i0 == 0) ? 1 : 0;
        for (int e = 0; e < NE; ++e) if (e != i0 && p[e] > p[i1]) i1 = e;
        double den = p[i0] + p[i1] + 1e-9;
        topk_i[t * 2] = i0; topk_i[t * 2 + 1] = i1;
        topk_w[t * 2] = (float)(p[i0] / den);
        topk_w[t * 2 + 1] = (float)(p[i1] / den);
        atomicAdd(&counts[i0], 1);
        atomicAdd(&counts[i1], 1);
    }
}

// ---------------- tiny prefix sums: row offsets + BM-row tile prefix
__global__ void offsets_kernel(const int* __restrict__ counts,
                               int* __restrict__ offs, int* __restrict__ ts)
{
    if (threadIdx.x == 0) {
        int s = 0, t = 0;
        for (int e = 0; e < NE; ++e) {
            offs[e] = s; ts[e] = t;
            s += counts[e];
            t += (counts[e] + BM - 1) / BM;
        }
        offs[NE] = s; ts[NE] = t;
    }
}

// ---------------- fused scatter + gather: one block per pair id; thread 0 claims
// the grouped row, whole block copies x row -> Xg (bf16). pair_tok eliminated.
__global__ __launch_bounds__(256) void scatter_gather_kernel(
    const float* __restrict__ x, const int* __restrict__ topk_i,
    const int* __restrict__ offs, int* __restrict__ cursor,
    int* __restrict__ inv_row, short* __restrict__ Xg)
{
    __shared__ int dsts;
    const int idx = blockIdx.x;               // pair id = t*2+k
    const int tid = threadIdx.x;
    if (tid == 0) {
        int e = topk_i[idx];
        int dst = offs[e] + atomicAdd(&cursor[e], 1);
        inv_row[idx] = dst;
        dsts = dst;
    }
    __syncthreads();
    const int dst = dsts;
    const int t = idx >> 1;
    float4 v = *(const float4*)&x[(size_t)t * HD + tid * 4];
    unsigned w0 = (unsigned)f2bf(v.x) | ((unsigned)f2bf(v.y) << 16);
    unsigned w1 = (unsigned)f2bf(v.z) | ((unsigned)f2bf(v.w) << 16);
    *(uint2*)&Xg[(size_t)dst * HD + tid * 4] = make_uint2(w0, w1);
}

// counted-vmcnt boundary: allow N loads (per wave) to stay in flight, then barrier.
#define WAITB(n) do {                                                   \
    asm volatile("s_waitcnt vmcnt(" #n ")" ::: "memory");               \
    __builtin_amdgcn_s_barrier();                                       \
    __builtin_amdgcn_sched_barrier(0);                                  \
} while (0)

#define GLOAD(srcp, dstp) __builtin_amdgcn_global_load_lds(                         \
        (const __attribute__((address_space(1))) unsigned*)(srcp),                  \
        (__attribute__((address_space(3))) unsigned*)(dstp), 16, 0, 0)

// ---------------- grouped GEMM, flat-tile balanced grid (r13), 4-SLOT LDS RING:
// prefetch 3 K-tiles ahead; boundary wait vmcnt(6) -> tile t+1's loads are TWO
// K-steps old (~1200+ cyc) > HBM latency (~900) -> exposed latency ~0 (r13's
// 3-slot ring waited on 1-K-step-old loads -> ~300+ cyc exposed per K-step; the
// r5-r13 20%-MfmaUtil plateau). 96 KB LDS -> 1 blk/CU, 8 waves (2M x 4N), wave
// tile 64x64. Granule swizzle (conflicts=0, r6/r7): phys 16B-granule g of row r
// holds global granule g^((r>>1)&3), pre-swizzled global source + swizzled
// ds_read addr (rule #21).
// EPI==1: gelu -> bf16 Hbuf ; EPI==2: +bias -> fp32 Op (both grouped rows)
template<int KDIM, int NDIM, int EPI>
__global__ __launch_bounds__(512, 1) void gemm_kernel(
    const short* __restrict__ A, const short* __restrict__ BT,
    const float* __restrict__ bias, void* __restrict__ outp,
    const int* __restrict__ counts, const int* __restrict__ offs,
    const int* __restrict__ ts)
{
    // bijective XCD swizzle (nwg % 8 == 0: 16*136=2176, 4*136=544)
    const int nwg = gridDim.x * gridDim.y;
    const int orig = blockIdx.y * gridDim.x + blockIdx.x;
    const int v = (orig & 7) * (nwg >> 3) + (orig >> 3);
    const int bx = v % gridDim.x;             // col tile
    const int j = v / gridDim.x;              // global row tile

    if (j >= ts[NE]) return;                  // inactive tail block (block-uniform)

    int e = 0;
    #pragma unroll
    for (int k = 1; k < NE; ++k) if (j >= ts[k]) e = k;
    const int cnt = counts[e];
    const int rt = j - ts[e];
    const int rowbase = offs[e] + rt * BM;
    const int colbase = bx * BN;

    const int tid = threadIdx.x;

    // 4-slot ring: As 4 x [128][32], Bs 4 x [256][32] -> 96 KB total
    __shared__ __align__(16) short As[4 * BM * BK];
    __shared__ __align__(16) short Bs[4 * BN * BK];

    const int lane = tid & 63;
    const int wv = tid >> 6;                  // 8 waves: 2 M-groups x 4 N-groups
    const int wr = (wv >> 2) * 64, wc = (wv & 3) * 64;
    const int l15 = lane & 15, l4 = lane >> 4;

    // staging: A = 4096 shorts (1 granule/thread), B = 8192 shorts (2 granules/thread)
    const int se0 = tid * 8;                  // LDS short index, rows 0..127
    const int sr0 = se0 >> 5;                 // staging row
    const int sg0 = (se0 >> 3) & 3;           // physical 16B granule within row
    const int sr1 = sr0 + 128;                // B pass 1 rows 128..255
    // pre-swizzled global k-offset (shorts): phys granule g holds global granule g^((r>>1)&3)
    const int sk0 = ((sg0 ^ ((sr0 >> 1) & 3)) << 3);
    const int sk1 = ((sg0 ^ ((sr1 >> 1) & 3)) << 3);

    // ds_read offsets (shorts), hoisted: logical granule l4 of row r at phys g = l4^((r>>1)&3)
    int aoff[4], boff[4];
    #pragma unroll
    for (int m = 0; m < 4; ++m) {
        int r = wr + m * 16 + l15;
        aoff[m] = r * BK + ((l4 ^ ((r >> 1) & 3)) << 3);
    }
    #pragma unroll
    for (int n = 0; n < 4; ++n) {
        int r = wc + n * 16 + l15;
        boff[n] = r * BK + ((l4 ^ ((r >> 1) & 3)) << 3);
    }

    const size_t bbase = (size_t)e * NDIM + colbase;

#define STAGE(sl, k0) do {                                                                \
        short* asl = &As[(sl) * (BM * BK)];                                               \
        short* bsl = &Bs[(sl) * (BN * BK)];                                               \
        const short* a0s = A + (size_t)(rowbase + sr0) * KDIM + (k0) + sk0;               \
        GLOAD(a0s, &asl[se0]);                                                            \
        const short* b0s = BT + (bbase + sr0) * KDIM + (k0) + sk0;                        \
        GLOAD(b0s, &bsl[se0]);                                                            \
        const short* b1s = BT + (bbase + sr1) * KDIM + (k0) + sk1;                        \
        GLOAD(b1s, &bsl[se0 + 4096]);                                                     \
    } while (0)

    constexpr int NT = KDIM / BK;             // 32 or 128 (>= 4)

    // prologue: stage tiles 0,1,2 (9 loads); wait tile 0 (allow 6 in flight)
    STAGE(0, 0);
    STAGE(1, BK);
    STAGE(2, 2 * BK);
    WAITB(6);

    f32x4 acc[4][4];
    #pragma unroll
    for (int m = 0; m < 4; ++m)
        #pragma unroll
        for (int n = 0; n < 4; ++n)
            acc[m][n] = (f32x4){0.f, 0.f, 0.f, 0.f};

    for (int t = 0; t < NT; ++t) {
        if (t + 3 < NT) STAGE((t + 3) & 3, (t + 3) * BK);   // 3-K-tile prefetch

        const short* asl = &As[(t & 3) * (BM * BK)];
        const short* bsl = &Bs[(t & 3) * (BN * BK)];
        bf16x8 a[4], b[4];
        #pragma unroll
        for (int m = 0; m < 4; ++m)
            a[m] = *(const bf16x8*)&asl[aoff[m]];
        #pragma unroll
        for (int n = 0; n < 4; ++n)
            b[n] = *(const bf16x8*)&bsl[boff[n]];

        __builtin_amdgcn_s_setprio(1);
        #pragma unroll
        for (int m = 0; m < 4; ++m)
            #pragma unroll
            for (int n = 0; n < 4; ++n)
                acc[m][n] = __builtin_amdgcn_mfma_f32_16x16x32_bf16(a[m], b[n], acc[m][n], 0, 0, 0);
        __builtin_amdgcn_s_setprio(0);

        // boundary into tile t+1 (staged 3 iters before -> 2 K-steps old at wait):
        // allow only the loads of tiles beyond t+1 to remain in flight.
        if (t < NT - 1) {
            if (t + 3 < NT)      WAITB(6);
            else if (t + 2 < NT) WAITB(3);
            else                 WAITB(0);
        }
    }
#undef STAGE

    const int rmax = cnt - rt * BM;   // valid rows in this tile (tail tiles < BM)

    if (EPI == 1) {
        short* Hb = (short*)outp;
        #pragma unroll
        for (int n = 0; n < 4; ++n) {
            int col = colbase + wc + n * 16 + l15;
            float bv = bias[e * NDIM + col];
            #pragma unroll
            for (int m = 0; m < 4; ++m) {
                int r0l = wr + m * 16 + l4 * 4;
                #pragma unroll
                for (int r = 0; r < 4; ++r) {
                    int rl = r0l + r;
                    if (rl < rmax) {   // guard: do NOT clobber next expert's rows
                        float vv = acc[m][n][r] + bv;
                        vv = 0.5f * vv * (1.0f + erff(vv * 0.70710678118654752f));
                        Hb[(size_t)(rowbase + rl) * NDIM + col] = (short)f2bf(vv);
                    }
                }
            }
        }
    } else {
        float* Op = (float*)outp;      // grouped-row order (coalesced tiles)
        #pragma unroll
        for (int n = 0; n < 4; ++n) {
            int col = colbase + wc + n * 16 + l15;
            float bv = bias[e * NDIM + col];
            #pragma unroll
            for (int m = 0; m < 4; ++m) {
                int r0l = wr + m * 16 + l4 * 4;
                #pragma unroll
                for (int r = 0; r < 4; ++r) {
                    int rl = r0l + r;
                    if (rl < rmax)
                        Op[(size_t)(rowbase + rl) * NDIM + col] = acc[m][n][r] + bv;
                }
            }
        }
    }
}

// ---------------- residual + LN + weighted top-k combine (Op in grouped order)
__device__ inline float block_sum256(float v, volatile float* red, int tid)
{
    #pragma unroll
    for (int o = 32; o > 0; o >>= 1) v += __shfl_xor(v, o, 64);
    __syncthreads();
    if ((tid & 63) == 0) red[tid >> 6] = v;
    __syncthreads();
    return red[0] + red[1] + red[2] + red[3];
}

__global__ __launch_bounds__(256) void ln_combine_kernel(
    const float* __restrict__ Op, const float* __restrict__ x,
    const int* __restrict__ topk_i, const float* __restrict__ topk_w,
    const int* __restrict__ inv_row,
    const float* __restrict__ ln_g, const float* __restrict__ ln_b,
    float* __restrict__ y)
{
    __shared__ float red[4];
    const int t = blockIdx.x, tid = threadIdx.x;
    const float4 xr = *(const float4*)&x[(size_t)t * HD + tid * 4];
    float a0 = 0.f, a1 = 0.f, a2 = 0.f, a3 = 0.f;
    #pragma unroll
    for (int k = 0; k < TOPK; ++k) {
        int e = topk_i[t * 2 + k];
        float w = topk_w[t * 2 + k];
        int grow = inv_row[t * 2 + k];
        const float4 o = *(const float4*)&Op[(size_t)grow * HD + tid * 4];
        float v0 = o.x + xr.x, v1 = o.y + xr.y, v2 = o.z + xr.z, v3 = o.w + xr.w;
        float s = block_sum256(v0 + v1 + v2 + v3, red, tid);
        float m = s * (1.0f / HD);
        float d0 = v0 - m, d1 = v1 - m, d2 = v2 - m, d3 = v3 - m;
        float ssq = block_sum256(d0 * d0 + d1 * d1 + d2 * d2 + d3 * d3, red, tid);
        float inv = 1.0f / sqrtf(ssq * (1.0f / HD) + 1e-5f);
        int base = e * HD + tid * 4;
        const float4 g = *(const float4*)&ln_g[base];
        const float4 bb = *(const float4*)&ln_b[base];
        a0 += w * (d0 * inv * g.x + bb.x);
        a1 += w * (d1 * inv * g.y + bb.y);
        a2 += w * (d2 * inv * g.z + bb.z);
        a3 += w * (d3 * inv * g.w + bb.w);
    }
    *(float4*)&y[(size_t)t * HD + tid * 4] = make_float4(a0, a1, a2, a3);
}

__global__ void zero_out_kernel(float* __restrict__ y, int n)
{
    int i = blockIdx.x * 256 + threadIdx.x;
    if (i < n) y[i] = 0.f;
}

extern "C" void kernel_launch(void* const* d_in, const int* in_sizes, int n_in,
                              void* d_out, int out_size, void* d_ws, size_t ws_size,
                              hipStream_t stream)
{
    const float* x      = (const float*)d_in[0];
    const float* W1     = (const float*)d_in[1];
    const float* b1     = (const float*)d_in[2];
    const float* W2     = (const float*)d_in[3];
    const float* b2     = (const float*)d_in[4];
    const float* ln_g   = (const float*)d_in[5];
    const float* ln_b   = (const float*)d_in[6];
    const float* gn_g   = (const float*)d_in[7];
    const float* gn_b   = (const float*)d_in[8];
    const float* gate_w = (const float*)d_in[9];
    const float* gate_b = (const float*)d_in[10];
    float* y = (float*)d_out;

    char* ws = (char*)d_ws;
    size_t off = 0;
    auto take = [&](size_t b) -> char* {
        char* p = ws + off;
        off = (off + b + 255) & ~(size_t)255;
        return p;
    };
    short* W1T     = (short*)take((size_t)NE * FD * HD * 2);       // [E][F][H] bf16
    short* W2T     = (short*)take((size_t)NE * HD * FD * 2);       // [E][H][F] bf16
    short* Xg      = (short*)take((size_t)(NPAIR + PADR) * HD * 2);
    short* Hb      = (short*)take((size_t)(NPAIR + PADR) * FD * 2);
    float* Op      = (float*)take((size_t)NPAIR * HD * 4);         // grouped rows
    int*   topk_i  = (int*)take(NPAIR * 4);
    float* topk_w  = (float*)take(NPAIR * 4);
    int*   cnts    = (int*)take(64);            // 8 counts + 8 cursor
    int*   cursor  = cnts + 8;
    int*   offs    = (int*)take(64);
    int*   ts      = (int*)take(64);            // tile prefix (BM=128)
    int*   inv_row = (int*)take((size_t)NPAIR * 4);

    if (ws_size < off) {   // workspace too small: emit zeros so failure mode is diagnosable
        zero_out_kernel<<<(out_size + 255) / 256, 256, 0, stream>>>(y, out_size);
        return;
    }

    hipMemsetAsync(cnts, 0, 64, stream);

    transpose_cvt_kernel<HD, FD><<<dim3(FD / 64, HD / 64, NE), 256, 0, stream>>>(W1, W1T);
    transpose_cvt_kernel<FD, HD><<<dim3(HD / 64, FD / 64, NE), 256, 0, stream>>>(W2, W2T);

    gating_kernel<<<TOK / 4, 256, 0, stream>>>(x, gn_g, gn_b, gate_w, gate_b, topk_i, topk_w, cnts);
    offsets_kernel<<<1, 64, 0, stream>>>(cnts, offs, ts);
    scatter_gather_kernel<<<NPAIR, 256, 0, stream>>>(x, topk_i, offs, cursor, inv_row, Xg);

    // Flat-tile balanced grouped GEMMs: grid = (cols, TMAX) with per-block ts[] lookup.
    // GEMM1: [pairs x HD] @ W1T -> gelu -> Hb   (16 x 136 = 2176 blocks)
    gemm_kernel<HD, FD, 1><<<dim3(FD / BN, TMAX), 512, 0, stream>>>(
        Xg, W1T, b1, (void*)Hb, cnts, offs, ts);
    // GEMM2: [pairs x FD] @ W2T -> +b2 -> Op   (4 x 136 = 544 blocks)
    gemm_kernel<FD, HD, 2><<<dim3(HD / BN, TMAX), 512, 0, stream>>>(
        Hb, W2T, b2, (void*)Op, cnts, offs, ts);

    ln_combine_kernel<<<TOK, 256, 0, stream>>>(Op, x, topk_i, topk_w, inv_row, ln_g, ln_b, y);
}

// Round 15
// 969.553 us; speedup vs baseline: 1.3121x; 1.3121x over previous
//
#include <hip/hip_runtime.h>
#include <hip/hip_bf16.h>

#define TOK   8192      // B*S
#define HD    1024      // H
#define FD    4096      // F
#define NE    8         // E
#define TOPK  2
#define NPAIR (TOK*TOPK)   // 16384, fixed
#define PADR  128          // row padding for tile overrun
#define BM    128
#define BN    256
#define BK    32
#define TMAX  (NPAIR/BM + NE)   // 136 grid rows; nwg stays %8==0

typedef short bf16x8 __attribute__((ext_vector_type(8)));
typedef float f32x4  __attribute__((ext_vector_type(4)));

__device__ inline unsigned short f2bf(float f) {
    unsigned u = __float_as_uint(f);
    unsigned r = (u + 0x7fffu + ((u >> 16) & 1u)) >> 16;
    return (unsigned short)r;
}

// ---------------- transpose + fp32->bf16 convert: in [E][R][C] -> out [E][C][R]
template<int R, int C>
__global__ __launch_bounds__(256) void transpose_cvt_kernel(
    const float* __restrict__ in, short* __restrict__ out)
{
    __shared__ float tile[64][65];
    const int tid = threadIdx.x;
    const int c0 = blockIdx.x * 64, r0 = blockIdx.y * 64, e = blockIdx.z;
    #pragma unroll
    for (int i = 0; i < 4; ++i) {
        int idx = i * 1024 + tid * 4;
        int rr = idx >> 6, cc = idx & 63;
        float4 v = *(const float4*)&in[((size_t)e * R + r0 + rr) * C + c0 + cc];
        tile[rr][cc] = v.x; tile[rr][cc + 1] = v.y;
        tile[rr][cc + 2] = v.z; tile[rr][cc + 3] = v.w;
    }
    __syncthreads();
    #pragma unroll
    for (int i = 0; i < 8; ++i) {
        int idx = i * 256 + tid;
        int cc = idx >> 5, rp = idx & 31;
        unsigned lo = f2bf(tile[rp * 2][cc]);
        unsigned hi = f2bf(tile[rp * 2 + 1][cc]);
        unsigned w = lo | (hi << 16);
        *(unsigned*)&out[((size_t)e * C + c0 + cc) * R + r0 + rp * 2] = w;
    }
}

// ---------------- gating: fp64 LN + logits + softmax + top-2 (one wave per token)
__global__ __launch_bounds__(256) void gating_kernel(
    const float* __restrict__ x, const float* __restrict__ gn_g, const float* __restrict__ gn_b,
    const float* __restrict__ gate_w, const float* __restrict__ gate_b,
    int* __restrict__ topk_i, float* __restrict__ topk_w, int* __restrict__ counts)
{
    const int wv = threadIdx.x >> 6, lane = threadIdx.x & 63;
    const int t = blockIdx.x * 4 + wv;
    const float* xr = x + (size_t)t * HD;

    double xs[16];
    #pragma unroll
    for (int i = 0; i < 16; ++i) xs[i] = (double)xr[i * 64 + lane];
    double s = 0.0;
    #pragma unroll
    for (int i = 0; i < 16; ++i) s += xs[i];
    #pragma unroll
    for (int o = 32; o > 0; o >>= 1) s += __shfl_xor(s, o, 64);
    double mean = s * (1.0 / HD);
    double ss = 0.0;
    #pragma unroll
    for (int i = 0; i < 16; ++i) { double d = xs[i] - mean; ss += d * d; }
    #pragma unroll
    for (int o = 32; o > 0; o >>= 1) ss += __shfl_xor(ss, o, 64);
    double inv = 1.0 / sqrt(ss * (1.0 / HD) + 1e-5);

    double ac[NE];
    #pragma unroll
    for (int e = 0; e < NE; ++e) ac[e] = 0.0;
    #pragma unroll
    for (int i = 0; i < 16; ++i) {
        int h = i * 64 + lane;
        double ln = (xs[i] - mean) * inv * (double)gn_g[h] + (double)gn_b[h];
        #pragma unroll
        for (int e = 0; e < NE; ++e) ac[e] += ln * (double)gate_w[h * NE + e];
    }
    #pragma unroll
    for (int e = 0; e < NE; ++e) {
        #pragma unroll
        for (int o = 32; o > 0; o >>= 1) ac[e] += __shfl_xor(ac[e], o, 64);
    }
    if (lane == 0) {
        double lg[NE], p[NE];
        double mx = -1e300;
        #pragma unroll
        for (int e = 0; e < NE; ++e) { lg[e] = ac[e] + (double)gate_b[e]; mx = lg[e] > mx ? lg[e] : mx; }
        double ps = 0.0;
        #pragma unroll
        for (int e = 0; e < NE; ++e) { p[e] = exp(lg[e] - mx); ps += p[e]; }
        #pragma unroll
        for (int e = 0; e < NE; ++e) p[e] /= ps;
        int i0 = 0;
        for (int e = 1; e < NE; ++e) if (p[e] > p[i0]) i0 = e;   // strict > keeps first (jax tie rule)
        int i1 = (i0 == 0) ? 1 : 0;
        for (int e = 0; e < NE; ++e) if (e != i0 && p[e] > p[i1]) i1 = e;
        double den = p[i0] + p[i1] + 1e-9;
        topk_i[t * 2] = i0; topk_i[t * 2 + 1] = i1;
        topk_w[t * 2] = (float)(p[i0] / den);
        topk_w[t * 2 + 1] = (float)(p[i1] / den);
        atomicAdd(&counts[i0], 1);
        atomicAdd(&counts[i1], 1);
    }
}

// ---------------- tiny prefix sums: row offsets + BM-row tile prefix
__global__ void offsets_kernel(const int* __restrict__ counts,
                               int* __restrict__ offs, int* __restrict__ ts)
{
    if (threadIdx.x == 0) {
        int s = 0, t = 0;
        for (int e = 0; e < NE; ++e) {
            offs[e] = s; ts[e] = t;
            s += counts[e];
            t += (counts[e] + BM - 1) / BM;
        }
        offs[NE] = s; ts[NE] = t;
    }
}

// ---------------- deterministic atomic-free binning: pass 1 = per-block histogram
__global__ __launch_bounds__(256) void hist_kernel(
    const int* __restrict__ topk_i, int* __restrict__ ghist)
{
    __shared__ int h[NE];
    const int b = blockIdx.x, tid = threadIdx.x;
    if (tid < NE) h[tid] = 0;
    __syncthreads();
    int e = topk_i[b * 256 + tid];
    atomicAdd(&h[e], 1);          // LDS atomic
    __syncthreads();
    if (tid < NE) ghist[b * NE + tid] = h[tid];
}

// pass 2: block base via prefix over ghist + stable within-block rank -> inv_row
__global__ __launch_bounds__(256) void scatter_kernel(
    const int* __restrict__ topk_i, const int* __restrict__ offs,
    const int* __restrict__ ghist, int* __restrict__ inv_row)
{
    __shared__ int baseS[NE];
    __shared__ unsigned char se[256];
    const int b = blockIdx.x, tid = threadIdx.x;
    const int idx = b * 256 + tid;
    const int e = topk_i[idx];
    if (tid < NE) {
        int s = offs[tid];
        for (int j = 0; j < b; ++j) s += ghist[j * NE + tid];
        baseS[tid] = s;
    }
    se[tid] = (unsigned char)e;
    __syncthreads();
    int rank = 0;
    for (int j = 0; j < tid; ++j) rank += (se[j] == (unsigned char)e);
    inv_row[idx] = baseS[e] + rank;
}

// ---------------- gather x rows (fp32) -> Xg (bf16, grouped order); 8 pairs/block
__global__ __launch_bounds__(256) void gather_kernel(
    const float* __restrict__ x, const int* __restrict__ inv_row, short* __restrict__ Xg)
{
    const int tid = threadIdx.x;
    #pragma unroll
    for (int i = 0; i < 8; ++i) {
        int p = blockIdx.x * 8 + i;
        int dst = inv_row[p];
        int t = p >> 1;
        float4 v = *(const float4*)&x[(size_t)t * HD + tid * 4];
        unsigned w0 = (unsigned)f2bf(v.x) | ((unsigned)f2bf(v.y) << 16);
        unsigned w1 = (unsigned)f2bf(v.z) | ((unsigned)f2bf(v.w) << 16);
        *(uint2*)&Xg[(size_t)dst * HD + tid * 4] = make_uint2(w0, w1);
    }
}

// counted-vmcnt boundary: allow N loads (per wave) to stay in flight, then barrier.
#define WAITB(n) do {                                                   \
    asm volatile("s_waitcnt vmcnt(" #n ")" ::: "memory");               \
    __builtin_amdgcn_s_barrier();                                       \
    __builtin_amdgcn_sched_barrier(0);                                  \
} while (0)

#define GLOAD(srcp, dstp) __builtin_amdgcn_global_load_lds(                         \
        (const __attribute__((address_space(1))) unsigned*)(srcp),                  \
        (__attribute__((address_space(3))) unsigned*)(dstp), 16, 0, 0)

// ---------------- grouped GEMM (r13 structure, best measured).
// MODE=0 full; MODE=1 stage-only ablation; MODE=2 compute-only ablation.
// EPI==1: gelu -> bf16 Hbuf ; EPI==2: +bias -> fp32 Op (both grouped rows)
template<int KDIM, int NDIM, int EPI, int MODE>
__global__ __launch_bounds__(512, 4) void gemm_kernel(
    const short* __restrict__ A, const short* __restrict__ BT,
    const float* __restrict__ bias, void* __restrict__ outp,
    const int* __restrict__ counts, const int* __restrict__ offs,
    const int* __restrict__ ts)
{
    // bijective XCD swizzle (nwg % 8 == 0: 16*136=2176, 4*136=544)
    const int nwg = gridDim.x * gridDim.y;
    const int orig = blockIdx.y * gridDim.x + blockIdx.x;
    const int v = (orig & 7) * (nwg >> 3) + (orig >> 3);
    const int bx = v % gridDim.x;             // col tile
    const int j = v / gridDim.x;              // global row tile

    if (j >= ts[NE]) return;                  // inactive tail block (block-uniform)

    int e = 0;
    #pragma unroll
    for (int k = 1; k < NE; ++k) if (j >= ts[k]) e = k;
    const int cnt = counts[e];
    const int rt = j - ts[e];
    const int rowbase = offs[e] + rt * BM;
    const int colbase = bx * BN;

    const int tid = threadIdx.x;

    // 3-slot ring: As 3 x [128][32], Bs 3 x [256][32] -> 72 KB total
    __shared__ __align__(16) short As[3 * BM * BK];
    __shared__ __align__(16) short Bs[3 * BN * BK];

    const int lane = tid & 63;
    const int wv = tid >> 6;                  // 8 waves: 2 M-groups x 4 N-groups
    const int wr = (wv >> 2) * 64, wc = (wv & 3) * 64;
    const int l15 = lane & 15, l4 = lane >> 4;

    // staging: A = 4096 shorts (1 granule/thread), B = 8192 shorts (2 granules/thread)
    const int se0 = tid * 8;                  // LDS short index, rows 0..127
    const int sr0 = se0 >> 5;                 // staging row
    const int sg0 = (se0 >> 3) & 3;           // physical 16B granule within row
    const int sr1 = sr0 + 128;                // B pass 1 rows 128..255
    // pre-swizzled global k-offset: phys granule g holds global granule g^((r>>1)&3)
    const int sk0 = ((sg0 ^ ((sr0 >> 1) & 3)) << 3);
    const int sk1 = ((sg0 ^ ((sr1 >> 1) & 3)) << 3);

    // ds_read offsets: logical granule l4 of row r at phys g = l4^((r>>1)&3)
    int aoff[4], boff[4];
    #pragma unroll
    for (int m = 0; m < 4; ++m) {
        int r = wr + m * 16 + l15;
        aoff[m] = r * BK + ((l4 ^ ((r >> 1) & 3)) << 3);
    }
    #pragma unroll
    for (int n = 0; n < 4; ++n) {
        int r = wc + n * 16 + l15;
        boff[n] = r * BK + ((l4 ^ ((r >> 1) & 3)) << 3);
    }

    const size_t bbase = (size_t)e * NDIM + colbase;

#define STAGE(sl, k0) do {                                                                \
        if (MODE != 2) {                                                                  \
        short* asl = &As[(sl) * (BM * BK)];                                               \
        short* bsl = &Bs[(sl) * (BN * BK)];                                               \
        const short* a0s = A + (size_t)(rowbase + sr0) * KDIM + (k0) + sk0;               \
        GLOAD(a0s, &asl[se0]);                                                            \
        const short* b0s = BT + (bbase + sr0) * KDIM + (k0) + sk0;                        \
        GLOAD(b0s, &bsl[se0]);                                                            \
        const short* b1s = BT + (bbase + sr1) * KDIM + (k0) + sk1;                        \
        GLOAD(b1s, &bsl[se0 + 4096]);                                                     \
        }                                                                                 \
    } while (0)

    constexpr int NT = KDIM / BK;

    // prologue: stage tiles 0 and 1; wait tile 0 (allow tile 1's 3 loads in flight)
    STAGE(0, 0);
    STAGE(1, BK);
    if (MODE != 2) { WAITB(3); } else { WAITB(0); }

    f32x4 acc[4][4];
    #pragma unroll
    for (int m = 0; m < 4; ++m)
        #pragma unroll
        for (int n = 0; n < 4; ++n)
            acc[m][n] = (f32x4){0.f, 0.f, 0.f, 0.f};

    for (int t = 0; t < NT; ++t) {
        if (t + 2 < NT) STAGE((t + 2) % 3, (t + 2) * BK);   // 2-K-tile prefetch

        if (MODE != 1) {
            const short* asl = &As[(t % 3) * (BM * BK)];
            const short* bsl = &Bs[(t % 3) * (BN * BK)];
            bf16x8 a[4], b[4];
            #pragma unroll
            for (int m = 0; m < 4; ++m)
                a[m] = *(const bf16x8*)&asl[aoff[m]];
            #pragma unroll
            for (int n = 0; n < 4; ++n)
                b[n] = *(const bf16x8*)&bsl[boff[n]];

            __builtin_amdgcn_s_setprio(1);
            #pragma unroll
            for (int m = 0; m < 4; ++m)
                #pragma unroll
                for (int n = 0; n < 4; ++n)
                    acc[m][n] = __builtin_amdgcn_mfma_f32_16x16x32_bf16(a[m], b[n], acc[m][n], 0, 0, 0);
            __builtin_amdgcn_s_setprio(0);
        }

        if (t < NT - 1) {
            if (MODE == 2)            { WAITB(0); }
            else if (t == NT - 2)     { WAITB(0); }
            else                      { WAITB(3); }
        }
    }
#undef STAGE

    if (MODE == 1) return;                    // stage-only: nothing to write
    if (MODE == 2) {                          // compute-only: keep acc live, no stores
        #pragma unroll
        for (int m = 0; m < 4; ++m)
            #pragma unroll
            for (int n = 0; n < 4; ++n)
                asm volatile("" :: "v"(acc[m][n][0]), "v"(acc[m][n][1]),
                                   "v"(acc[m][n][2]), "v"(acc[m][n][3]));
        return;
    }

    const int rmax = cnt - rt * BM;   // valid rows in this tile (tail tiles < BM)

    if (EPI == 1) {
        short* Hb = (short*)outp;
        #pragma unroll
        for (int n = 0; n < 4; ++n) {
            int col = colbase + wc + n * 16 + l15;
            float bv = bias[e * NDIM + col];
            #pragma unroll
            for (int m = 0; m < 4; ++m) {
                int r0l = wr + m * 16 + l4 * 4;
                #pragma unroll
                for (int r = 0; r < 4; ++r) {
                    int rl = r0l + r;
                    if (rl < rmax) {   // guard: do NOT clobber next expert's rows
                        float vv = acc[m][n][r] + bv;
                        vv = 0.5f * vv * (1.0f + erff(vv * 0.70710678118654752f));
                        Hb[(size_t)(rowbase + rl) * NDIM + col] = (short)f2bf(vv);
                    }
                }
            }
        }
    } else {
        float* Op = (float*)outp;      // grouped-row order (coalesced tiles)
        #pragma unroll
        for (int n = 0; n < 4; ++n) {
            int col = colbase + wc + n * 16 + l15;
            float bv = bias[e * NDIM + col];
            #pragma unroll
            for (int m = 0; m < 4; ++m) {
                int r0l = wr + m * 16 + l4 * 4;
                #pragma unroll
                for (int r = 0; r < 4; ++r) {
                    int rl = r0l + r;
                    if (rl < rmax)
                        Op[(size_t)(rowbase + rl) * NDIM + col] = acc[m][n][r] + bv;
                }
            }
        }
    }
}

// ---------------- residual + LN + weighted top-k combine (Op in grouped order)
__device__ inline float block_sum256(float v, volatile float* red, int tid)
{
    #pragma unroll
    for (int o = 32; o > 0; o >>= 1) v += __shfl_xor(v, o, 64);
    __syncthreads();
    if ((tid & 63) == 0) red[tid >> 6] = v;
    __syncthreads();
    return red[0] + red[1] + red[2] + red[3];
}

__global__ __launch_bounds__(256) void ln_combine_kernel(
    const float* __restrict__ Op, const float* __restrict__ x,
    const int* __restrict__ topk_i, const float* __restrict__ topk_w,
    const int* __restrict__ inv_row,
    const float* __restrict__ ln_g, const float* __restrict__ ln_b,
    float* __restrict__ y)
{
    __shared__ float red[4];
    const int t = blockIdx.x, tid = threadIdx.x;
    const float4 xr = *(const float4*)&x[(size_t)t * HD + tid * 4];
    float a0 = 0.f, a1 = 0.f, a2 = 0.f, a3 = 0.f;
    #pragma unroll
    for (int k = 0; k < TOPK; ++k) {
        int e = topk_i[t * 2 + k];
        float w = topk_w[t * 2 + k];
        int grow = inv_row[t * 2 + k];
        const float4 o = *(const float4*)&Op[(size_t)grow * HD + tid * 4];
        float v0 = o.x + xr.x, v1 = o.y + xr.y, v2 = o.z + xr.z, v3 = o.w + xr.w;
        float s = block_sum256(v0 + v1 + v2 + v3, red, tid);
        float m = s * (1.0f / HD);
        float d0 = v0 - m, d1 = v1 - m, d2 = v2 - m, d3 = v3 - m;
        float ssq = block_sum256(d0 * d0 + d1 * d1 + d2 * d2 + d3 * d3, red, tid);
        float inv = 1.0f / sqrtf(ssq * (1.0f / HD) + 1e-5f);
        int base = e * HD + tid * 4;
        const float4 g = *(const float4*)&ln_g[base];
        const float4 bb = *(const float4*)&ln_b[base];
        a0 += w * (d0 * inv * g.x + bb.x);
        a1 += w * (d1 * inv * g.y + bb.y);
        a2 += w * (d2 * inv * g.z + bb.z);
        a3 += w * (d3 * inv * g.w + bb.w);
    }
    *(float4*)&y[(size_t)t * HD + tid * 4] = make_float4(a0, a1, a2, a3);
}

__global__ void zero_out_kernel(float* __restrict__ y, int n)
{
    int i = blockIdx.x * 256 + threadIdx.x;
    if (i < n) y[i] = 0.f;
}

extern "C" void kernel_launch(void* const* d_in, const int* in_sizes, int n_in,
                              void* d_out, int out_size, void* d_ws, size_t ws_size,
                              hipStream_t stream)
{
    const float* x      = (const float*)d_in[0];
    const float* W1     = (const float*)d_in[1];
    const float* b1     = (const float*)d_in[2];
    const float* W2     = (const float*)d_in[3];
    const float* b2     = (const float*)d_in[4];
    const float* ln_g   = (const float*)d_in[5];
    const float* ln_b   = (const float*)d_in[6];
    const float* gn_g   = (const float*)d_in[7];
    const float* gn_b   = (const float*)d_in[8];
    const float* gate_w = (const float*)d_in[9];
    const float* gate_b = (const float*)d_in[10];
    float* y = (float*)d_out;

    char* ws = (char*)d_ws;
    size_t off = 0;
    auto take = [&](size_t b) -> char* {
        char* p = ws + off;
        off = (off + b + 255) & ~(size_t)255;
        return p;
    };
    short* W1T     = (short*)take((size_t)NE * FD * HD * 2);       // [E][F][H] bf16
    short* W2T     = (short*)take((size_t)NE * HD * FD * 2);       // [E][H][F] bf16
    short* Xg      = (short*)take((size_t)(NPAIR + PADR) * HD * 2);
    short* Hb      = (short*)take((size_t)(NPAIR + PADR) * FD * 2);
    float* Op      = (float*)take((size_t)NPAIR * HD * 4);         // grouped rows
    int*   topk_i  = (int*)take(NPAIR * 4);
    float* topk_w  = (float*)take(NPAIR * 4);
    int*   cnts    = (int*)take(64);
    int*   offs    = (int*)take(64);
    int*   ts      = (int*)take(64);            // tile prefix (BM=128)
    int*   ghist   = (int*)take(64 * NE * 4);   // per-block histograms
    int*   inv_row = (int*)take((size_t)NPAIR * 4);

    if (ws_size < off) {   // workspace too small: emit zeros so failure mode is diagnosable
        zero_out_kernel<<<(out_size + 255) / 256, 256, 0, stream>>>(y, out_size);
        return;
    }

    hipMemsetAsync(cnts, 0, 64, stream);

    transpose_cvt_kernel<HD, FD><<<dim3(FD / 64, HD / 64, NE), 256, 0, stream>>>(W1, W1T);
    transpose_cvt_kernel<FD, HD><<<dim3(HD / 64, FD / 64, NE), 256, 0, stream>>>(W2, W2T);

    gating_kernel<<<TOK / 4, 256, 0, stream>>>(x, gn_g, gn_b, gate_w, gate_b, topk_i, topk_w, cnts);
    offsets_kernel<<<1, 64, 0, stream>>>(cnts, offs, ts);
    hist_kernel<<<NPAIR / 256, 256, 0, stream>>>(topk_i, ghist);
    scatter_kernel<<<NPAIR / 256, 256, 0, stream>>>(topk_i, offs, ghist, inv_row);
    gather_kernel<<<NPAIR / 8, 256, 0, stream>>>(x, inv_row, Xg);

    // Flat-tile balanced grouped GEMMs (r13 config).
    gemm_kernel<HD, FD, 1, 0><<<dim3(FD / BN, TMAX), 512, 0, stream>>>(
        Xg, W1T, b1, (void*)Hb, cnts, offs, ts);
    gemm_kernel<FD, HD, 2, 0><<<dim3(HD / BN, TMAX), 512, 0, stream>>>(
        Hb, W2T, b2, (void*)Op, cnts, offs, ts);

    ln_combine_kernel<<<TOK, 256, 0, stream>>>(Op, x, topk_i, topk_w, inv_row, ln_g, ln_b, y);

    // ---- ablation probes (GEMM2 config, 1/4 grid, read-only, no observable writes) ----
    gemm_kernel<FD, HD, 2, 1><<<dim3(HD / BN, 32), 512, 0, stream>>>(   // stage-only
        Hb, W2T, b2, (void*)Op, cnts, offs, ts);
    gemm_kernel<FD, HD, 2, 2><<<dim3(HD / BN, 32), 512, 0, stream>>>(   // compute-only
        Hb, W2T, b2, (void*)Op, cnts, offs, ts);
}

// Round 16
// 754.253 us; speedup vs baseline: 1.6866x; 1.2854x over previous
//
#include <hip/hip_runtime.h>
#include <hip/hip_bf16.h>

#define TOK   8192      // B*S
#define HD    1024      // H
#define FD    4096      // F
#define NE    8         // E
#define TOPK  2
#define NPAIR (TOK*TOPK)   // 16384, fixed
#define PADR  128          // row padding for tile overrun
#define BM    128
#define BN    256
#define BK    32
#define TMAX  (NPAIR/BM + NE)   // 136 grid rows; nwg stays %8==0
#define CSTR  276               // C-staging LDS row stride (shorts): 4-row step = 8 banks

typedef short bf16x8 __attribute__((ext_vector_type(8)));
typedef float f32x4  __attribute__((ext_vector_type(4)));

__device__ inline unsigned short f2bf(float f) {
    unsigned u = __float_as_uint(f);
    unsigned r = (u + 0x7fffu + ((u >> 16) & 1u)) >> 16;
    return (unsigned short)r;
}

// ---------------- transpose + fp32->bf16 convert: in [E][R][C] -> out [E][C][R]
// read float4, write uint4 (16B) -> bandwidth-optimal both phases
template<int R, int C>
__global__ __launch_bounds__(256) void transpose_cvt_kernel(
    const float* __restrict__ in, short* __restrict__ out)
{
    __shared__ float tile[64][65];
    const int tid = threadIdx.x;
    const int c0 = blockIdx.x * 64, r0 = blockIdx.y * 64, e = blockIdx.z;
    #pragma unroll
    for (int i = 0; i < 4; ++i) {
        int idx = i * 1024 + tid * 4;
        int rr = idx >> 6, cc = idx & 63;
        float4 v = *(const float4*)&in[((size_t)e * R + r0 + rr) * C + c0 + cc];
        tile[rr][cc] = v.x; tile[rr][cc + 1] = v.y;
        tile[rr][cc + 2] = v.z; tile[rr][cc + 3] = v.w;
    }
    __syncthreads();
    #pragma unroll
    for (int i = 0; i < 2; ++i) {
        int idx = i * 256 + tid;
        int cc = idx >> 3, rb = (idx & 7) * 8;   // col, 8-row chunk
        uint4 w;
        w.x = (unsigned)f2bf(tile[rb + 0][cc]) | ((unsigned)f2bf(tile[rb + 1][cc]) << 16);
        w.y = (unsigned)f2bf(tile[rb + 2][cc]) | ((unsigned)f2bf(tile[rb + 3][cc]) << 16);
        w.z = (unsigned)f2bf(tile[rb + 4][cc]) | ((unsigned)f2bf(tile[rb + 5][cc]) << 16);
        w.w = (unsigned)f2bf(tile[rb + 6][cc]) | ((unsigned)f2bf(tile[rb + 7][cc]) << 16);
        *(uint4*)&out[((size_t)e * C + c0 + cc) * R + r0 + rb] = w;
    }
}

// ---------------- gating: fp64 LN + logits + softmax + top-2 (one wave per token)
__global__ __launch_bounds__(256) void gating_kernel(
    const float* __restrict__ x, const float* __restrict__ gn_g, const float* __restrict__ gn_b,
    const float* __restrict__ gate_w, const float* __restrict__ gate_b,
    int* __restrict__ topk_i, float* __restrict__ topk_w, int* __restrict__ counts)
{
    const int wv = threadIdx.x >> 6, lane = threadIdx.x & 63;
    const int t = blockIdx.x * 4 + wv;
    const float* xr = x + (size_t)t * HD;

    double xs[16];
    #pragma unroll
    for (int i = 0; i < 16; ++i) xs[i] = (double)xr[i * 64 + lane];
    double s = 0.0;
    #pragma unroll
    for (int i = 0; i < 16; ++i) s += xs[i];
    #pragma unroll
    for (int o = 32; o > 0; o >>= 1) s += __shfl_xor(s, o, 64);
    double mean = s * (1.0 / HD);
    double ss = 0.0;
    #pragma unroll
    for (int i = 0; i < 16; ++i) { double d = xs[i] - mean; ss += d * d; }
    #pragma unroll
    for (int o = 32; o > 0; o >>= 1) ss += __shfl_xor(ss, o, 64);
    double inv = 1.0 / sqrt(ss * (1.0 / HD) + 1e-5);

    double ac[NE];
    #pragma unroll
    for (int e = 0; e < NE; ++e) ac[e] = 0.0;
    #pragma unroll
    for (int i = 0; i < 16; ++i) {
        int h = i * 64 + lane;
        double ln = (xs[i] - mean) * inv * (double)gn_g[h] + (double)gn_b[h];
        #pragma unroll
        for (int e = 0; e < NE; ++e) ac[e] += ln * (double)gate_w[h * NE + e];
    }
    #pragma unroll
    for (int e = 0; e < NE; ++e) {
        #pragma unroll
        for (int o = 32; o > 0; o >>= 1) ac[e] += __shfl_xor(ac[e], o, 64);
    }
    if (lane == 0) {
        double lg[NE], p[NE];
        double mx = -1e300;
        #pragma unroll
        for (int e = 0; e < NE; ++e) { lg[e] = ac[e] + (double)gate_b[e]; mx = lg[e] > mx ? lg[e] : mx; }
        double ps = 0.0;
        #pragma unroll
        for (int e = 0; e < NE; ++e) { p[e] = exp(lg[e] - mx); ps += p[e]; }
        #pragma unroll
        for (int e = 0; e < NE; ++e) p[e] /= ps;
        int i0 = 0;
        for (int e = 1; e < NE; ++e) if (p[e] > p[i0]) i0 = e;   // strict > keeps first (jax tie rule)
        int i1 = (i0 == 0) ? 1 : 0;
        for (int e = 0; e < NE; ++e) if (e != i0 && p[e] > p[i1]) i1 = e;
        double den = p[i0] + p[i1] + 1e-9;
        topk_i[t * 2] = i0; topk_i[t * 2 + 1] = i1;
        topk_w[t * 2] = (float)(p[i0] / den);
        topk_w[t * 2 + 1] = (float)(p[i1] / den);
        atomicAdd(&counts[i0], 1);
        atomicAdd(&counts[i1], 1);
    }
}

// ---------------- tiny prefix sums: row offsets + BM-row tile prefix
__global__ void offsets_kernel(const int* __restrict__ counts,
                               int* __restrict__ offs, int* __restrict__ ts)
{
    if (threadIdx.x == 0) {
        int s = 0, t = 0;
        for (int e = 0; e < NE; ++e) {
            offs[e] = s; ts[e] = t;
            s += counts[e];
            t += (counts[e] + BM - 1) / BM;
        }
        offs[NE] = s; ts[NE] = t;
    }
}

// ---------------- deterministic atomic-free binning: pass 1 = per-block histogram
__global__ __launch_bounds__(256) void hist_kernel(
    const int* __restrict__ topk_i, int* __restrict__ ghist)
{
    __shared__ int h[NE];
    const int b = blockIdx.x, tid = threadIdx.x;
    if (tid < NE) h[tid] = 0;
    __syncthreads();
    int e = topk_i[b * 256 + tid];
    atomicAdd(&h[e], 1);          // LDS atomic
    __syncthreads();
    if (tid < NE) ghist[b * NE + tid] = h[tid];
}

// pass 2: block base via prefix over ghist + stable within-block rank -> inv_row
__global__ __launch_bounds__(256) void scatter_kernel(
    const int* __restrict__ topk_i, const int* __restrict__ offs,
    const int* __restrict__ ghist, int* __restrict__ inv_row)
{
    __shared__ int baseS[NE];
    __shared__ unsigned char se[256];
    const int b = blockIdx.x, tid = threadIdx.x;
    const int idx = b * 256 + tid;
    const int e = topk_i[idx];
    if (tid < NE) {
        int s = offs[tid];
        for (int j = 0; j < b; ++j) s += ghist[j * NE + tid];
        baseS[tid] = s;
    }
    se[tid] = (unsigned char)e;
    __syncthreads();
    int rank = 0;
    for (int j = 0; j < tid; ++j) rank += (se[j] == (unsigned char)e);
    inv_row[idx] = baseS[e] + rank;
}

// ---------------- gather x rows (fp32) -> Xg (bf16, grouped order); 8 pairs/block
__global__ __launch_bounds__(256) void gather_kernel(
    const float* __restrict__ x, const int* __restrict__ inv_row, short* __restrict__ Xg)
{
    const int tid = threadIdx.x;
    #pragma unroll
    for (int i = 0; i < 8; ++i) {
        int p = blockIdx.x * 8 + i;
        int dst = inv_row[p];
        int t = p >> 1;
        float4 v = *(const float4*)&x[(size_t)t * HD + tid * 4];
        unsigned w0 = (unsigned)f2bf(v.x) | ((unsigned)f2bf(v.y) << 16);
        unsigned w1 = (unsigned)f2bf(v.z) | ((unsigned)f2bf(v.w) << 16);
        *(uint2*)&Xg[(size_t)dst * HD + tid * 4] = make_uint2(w0, w1);
    }
}

// counted-vmcnt boundary: allow N loads (per wave) to stay in flight, then barrier.
#define WAITB(n) do {                                                   \
    asm volatile("s_waitcnt vmcnt(" #n ")" ::: "memory");               \
    __builtin_amdgcn_s_barrier();                                       \
    __builtin_amdgcn_sched_barrier(0);                                  \
} while (0)

#define GLOAD(srcp, dstp) __builtin_amdgcn_global_load_lds(                         \
        (const __attribute__((address_space(1))) unsigned*)(srcp),                  \
        (__attribute__((address_space(3))) unsigned*)(dstp), 16, 0, 0)

// ---------------- grouped GEMM (r13 structure, best measured), with LDS-staged
// C epilogue for EPI==1 (fixes the 2.2x WRITE amplification: 32B strided bf16
// segments -> 512B row-major uint4 stores; Smem reused after final barrier).
// EPI==1: gelu -> bf16 Hbuf ; EPI==2: +bias -> fp32 Op (both grouped rows)
template<int KDIM, int NDIM, int EPI>
__global__ __launch_bounds__(512, 4) void gemm_kernel(
    const short* __restrict__ A, const short* __restrict__ BT,
    const float* __restrict__ bias, void* __restrict__ outp,
    const int* __restrict__ counts, const int* __restrict__ offs,
    const int* __restrict__ ts)
{
    // bijective XCD swizzle (nwg % 8 == 0: 16*136=2176, 4*136=544)
    const int nwg = gridDim.x * gridDim.y;
    const int orig = blockIdx.y * gridDim.x + blockIdx.x;
    const int v = (orig & 7) * (nwg >> 3) + (orig >> 3);
    const int bx = v % gridDim.x;             // col tile
    const int j = v / gridDim.x;              // global row tile

    if (j >= ts[NE]) return;                  // inactive tail block (block-uniform)

    int e = 0;
    #pragma unroll
    for (int k = 1; k < NE; ++k) if (j >= ts[k]) e = k;
    const int cnt = counts[e];
    const int rt = j - ts[e];
    const int rowbase = offs[e] + rt * BM;
    const int colbase = bx * BN;

    const int tid = threadIdx.x;

    // 72 KB shared pool: K-loop = As(24KB) + Bs(48KB); epilogue reuses it as
    // C staging (128 x CSTR shorts = 69 KB)
    __shared__ __align__(16) short Smem[3 * BM * BK + 3 * BN * BK];
    short* As = Smem;
    short* Bs = Smem + 3 * BM * BK;

    const int lane = tid & 63;
    const int wv = tid >> 6;                  // 8 waves: 2 M-groups x 4 N-groups
    const int wr = (wv >> 2) * 64, wc = (wv & 3) * 64;
    const int l15 = lane & 15, l4 = lane >> 4;

    // staging: A = 4096 shorts (1 granule/thread), B = 8192 shorts (2 granules/thread)
    const int se0 = tid * 8;                  // LDS short index, rows 0..127
    const int sr0 = se0 >> 5;                 // staging row
    const int sg0 = (se0 >> 3) & 3;           // physical 16B granule within row
    const int sr1 = sr0 + 128;                // B pass 1 rows 128..255
    // pre-swizzled global k-offset: phys granule g holds global granule g^((r>>1)&3)
    const int sk0 = ((sg0 ^ ((sr0 >> 1) & 3)) << 3);
    const int sk1 = ((sg0 ^ ((sr1 >> 1) & 3)) << 3);

    // ds_read offsets: logical granule l4 of row r at phys g = l4^((r>>1)&3)
    int aoff[4], boff[4];
    #pragma unroll
    for (int m = 0; m < 4; ++m) {
        int r = wr + m * 16 + l15;
        aoff[m] = r * BK + ((l4 ^ ((r >> 1) & 3)) << 3);
    }
    #pragma unroll
    for (int n = 0; n < 4; ++n) {
        int r = wc + n * 16 + l15;
        boff[n] = r * BK + ((l4 ^ ((r >> 1) & 3)) << 3);
    }

    const size_t bbase = (size_t)e * NDIM + colbase;

#define STAGE(sl, k0) do {                                                                \
        short* asl = &As[(sl) * (BM * BK)];                                               \
        short* bsl = &Bs[(sl) * (BN * BK)];                                               \
        const short* a0s = A + (size_t)(rowbase + sr0) * KDIM + (k0) + sk0;               \
        GLOAD(a0s, &asl[se0]);                                                            \
        const short* b0s = BT + (bbase + sr0) * KDIM + (k0) + sk0;                        \
        GLOAD(b0s, &bsl[se0]);                                                            \
        const short* b1s = BT + (bbase + sr1) * KDIM + (k0) + sk1;                        \
        GLOAD(b1s, &bsl[se0 + 4096]);                                                     \
    } while (0)

    constexpr int NT = KDIM / BK;

    // prologue: stage tiles 0 and 1; wait tile 0 (allow tile 1's 3 loads in flight)
    STAGE(0, 0);
    STAGE(1, BK);
    WAITB(3);

    f32x4 acc[4][4];
    #pragma unroll
    for (int m = 0; m < 4; ++m)
        #pragma unroll
        for (int n = 0; n < 4; ++n)
            acc[m][n] = (f32x4){0.f, 0.f, 0.f, 0.f};

    for (int t = 0; t < NT; ++t) {
        if (t + 2 < NT) STAGE((t + 2) % 3, (t + 2) * BK);   // 2-K-tile prefetch

        const short* asl = &As[(t % 3) * (BM * BK)];
        const short* bsl = &Bs[(t % 3) * (BN * BK)];
        bf16x8 a[4], b[4];
        #pragma unroll
        for (int m = 0; m < 4; ++m)
            a[m] = *(const bf16x8*)&asl[aoff[m]];
        #pragma unroll
        for (int n = 0; n < 4; ++n)
            b[n] = *(const bf16x8*)&bsl[boff[n]];

        __builtin_amdgcn_s_setprio(1);
        #pragma unroll
        for (int m = 0; m < 4; ++m)
            #pragma unroll
            for (int n = 0; n < 4; ++n)
                acc[m][n] = __builtin_amdgcn_mfma_f32_16x16x32_bf16(a[m], b[n], acc[m][n], 0, 0, 0);
        __builtin_amdgcn_s_setprio(0);

        if (t < NT - 1) {
            if (t == NT - 2) WAITB(0); else WAITB(3);
        }
    }
#undef STAGE

    const int rmax = cnt - rt * BM;   // valid rows in this tile (tail tiles < BM)

    if (EPI == 1) {
        short* Hb = (short*)outp;
        __syncthreads();              // all waves done reading As/Bs -> reuse as C staging
        short* Cs = Smem;             // [128][CSTR] shorts
        #pragma unroll
        for (int n = 0; n < 4; ++n) {
            int col = wc + n * 16 + l15;
            float bv = bias[e * NDIM + colbase + col];
            #pragma unroll
            for (int m = 0; m < 4; ++m) {
                int r0l = wr + m * 16 + l4 * 4;
                #pragma unroll
                for (int r = 0; r < 4; ++r) {
                    float vv = acc[m][n][r] + bv;
                    vv = 0.5f * vv * (1.0f + erff(vv * 0.70710678118654752f));
                    Cs[(r0l + r) * CSTR + col] = (short)f2bf(vv);
                }
            }
        }
        __syncthreads();
        // copy out: 8 iters x 512 threads x 16B; row = i*16 + (tid>>5), col = (tid&31)*8
        const int crow0 = tid >> 5, ccol = (tid & 31) * 8;
        #pragma unroll
        for (int i = 0; i < 8; ++i) {
            int row = i * 16 + crow0;
            if (row < rmax) {
                const short* src = &Cs[row * CSTR + ccol];
                *(uint4*)&Hb[(size_t)(rowbase + row) * NDIM + colbase + ccol] =
                    *(const uint4*)src;
            }
        }
    } else {
        float* Op = (float*)outp;      // grouped-row order (coalesced tiles)
        #pragma unroll
        for (int n = 0; n < 4; ++n) {
            int col = colbase + wc + n * 16 + l15;
            float bv = bias[e * NDIM + col];
            #pragma unroll
            for (int m = 0; m < 4; ++m) {
                int r0l = wr + m * 16 + l4 * 4;
                #pragma unroll
                for (int r = 0; r < 4; ++r) {
                    int rl = r0l + r;
                    if (rl < rmax)
                        Op[(size_t)(rowbase + rl) * NDIM + col] = acc[m][n][r] + bv;
                }
            }
        }
    }
}

// ---------------- residual + LN + weighted top-k combine (Op in grouped order)
__device__ inline float block_sum256(float v, volatile float* red, int tid)
{
    #pragma unroll
    for (int o = 32; o > 0; o >>= 1) v += __shfl_xor(v, o, 64);
    __syncthreads();
    if ((tid & 63) == 0) red[tid >> 6] = v;
    __syncthreads();
    return red[0] + red[1] + red[2] + red[3];
}

__global__ __launch_bounds__(256) void ln_combine_kernel(
    const float* __restrict__ Op, const float* __restrict__ x,
    const int* __restrict__ topk_i, const float* __restrict__ topk_w,
    const int* __restrict__ inv_row,
    const float* __restrict__ ln_g, const float* __restrict__ ln_b,
    float* __restrict__ y)
{
    __shared__ float red[4];
    const int t = blockIdx.x, tid = threadIdx.x;
    const float4 xr = *(const float4*)&x[(size_t)t * HD + tid * 4];
    float a0 = 0.f, a1 = 0.f, a2 = 0.f, a3 = 0.f;
    #pragma unroll
    for (int k = 0; k < TOPK; ++k) {
        int e = topk_i[t * 2 + k];
        float w = topk_w[t * 2 + k];
        int grow = inv_row[t * 2 + k];
        const float4 o = *(const float4*)&Op[(size_t)grow * HD + tid * 4];
        float v0 = o.x + xr.x, v1 = o.y + xr.y, v2 = o.z + xr.z, v3 = o.w + xr.w;
        float s = block_sum256(v0 + v1 + v2 + v3, red, tid);
        float m = s * (1.0f / HD);
        float d0 = v0 - m, d1 = v1 - m, d2 = v2 - m, d3 = v3 - m;
        float ssq = block_sum256(d0 * d0 + d1 * d1 + d2 * d2 + d3 * d3, red, tid);
        float inv = 1.0f / sqrtf(ssq * (1.0f / HD) + 1e-5f);
        int base = e * HD + tid * 4;
        const float4 g = *(const float4*)&ln_g[base];
        const float4 bb = *(const float4*)&ln_b[base];
        a0 += w * (d0 * inv * g.x + bb.x);
        a1 += w * (d1 * inv * g.y + bb.y);
        a2 += w * (d2 * inv * g.z + bb.z);
        a3 += w * (d3 * inv * g.w + bb.w);
    }
    *(float4*)&y[(size_t)t * HD + tid * 4] = make_float4(a0, a1, a2, a3);
}

__global__ void zero_out_kernel(float* __restrict__ y, int n)
{
    int i = blockIdx.x * 256 + threadIdx.x;
    if (i < n) y[i] = 0.f;
}

extern "C" void kernel_launch(void* const* d_in, const int* in_sizes, int n_in,
                              void* d_out, int out_size, void* d_ws, size_t ws_size,
                              hipStream_t stream)
{
    const float* x      = (const float*)d_in[0];
    const float* W1     = (const float*)d_in[1];
    const float* b1     = (const float*)d_in[2];
    const float* W2     = (const float*)d_in[3];
    const float* b2     = (const float*)d_in[4];
    const float* ln_g   = (const float*)d_in[5];
    const float* ln_b   = (const float*)d_in[6];
    const float* gn_g   = (const float*)d_in[7];
    const float* gn_b   = (const float*)d_in[8];
    const float* gate_w = (const float*)d_in[9];
    const float* gate_b = (const float*)d_in[10];
    float* y = (float*)d_out;

    char* ws = (char*)d_ws;
    size_t off = 0;
    auto take = [&](size_t b) -> char* {
        char* p = ws + off;
        off = (off + b + 255) & ~(size_t)255;
        return p;
    };
    short* W1T     = (short*)take((size_t)NE * FD * HD * 2);       // [E][F][H] bf16
    short* W2T     = (short*)take((size_t)NE * HD * FD * 2);       // [E][H][F] bf16
    short* Xg      = (short*)take((size_t)(NPAIR + PADR) * HD * 2);
    short* Hb      = (short*)take((size_t)(NPAIR + PADR) * FD * 2);
    float* Op      = (float*)take((size_t)NPAIR * HD * 4);         // grouped rows
    int*   topk_i  = (int*)take(NPAIR * 4);
    float* topk_w  = (float*)take(NPAIR * 4);
    int*   cnts    = (int*)take(64);
    int*   offs    = (int*)take(64);
    int*   ts      = (int*)take(64);            // tile prefix (BM=128)
    int*   ghist   = (int*)take(64 * NE * 4);   // per-block histograms
    int*   inv_row = (int*)take((size_t)NPAIR * 4);

    if (ws_size < off) {   // workspace too small: emit zeros so failure mode is diagnosable
        zero_out_kernel<<<(out_size + 255) / 256, 256, 0, stream>>>(y, out_size);
        return;
    }

    hipMemsetAsync(cnts, 0, 64, stream);

    transpose_cvt_kernel<HD, FD><<<dim3(FD / 64, HD / 64, NE), 256, 0, stream>>>(W1, W1T);
    transpose_cvt_kernel<FD, HD><<<dim3(HD / 64, FD / 64, NE), 256, 0, stream>>>(W2, W2T);

    gating_kernel<<<TOK / 4, 256, 0, stream>>>(x, gn_g, gn_b, gate_w, gate_b, topk_i, topk_w, cnts);
    offsets_kernel<<<1, 64, 0, stream>>>(cnts, offs, ts);
    hist_kernel<<<NPAIR / 256, 256, 0, stream>>>(topk_i, ghist);
    scatter_kernel<<<NPAIR / 256, 256, 0, stream>>>(topk_i, offs, ghist, inv_row);
    gather_kernel<<<NPAIR / 8, 256, 0, stream>>>(x, inv_row, Xg);

    // Flat-tile balanced grouped GEMMs (r13 config).
    gemm_kernel<HD, FD, 1><<<dim3(FD / BN, TMAX), 512, 0, stream>>>(
        Xg, W1T, b1, (void*)Hb, cnts, offs, ts);
    gemm_kernel<FD, HD, 2><<<dim3(HD / BN, TMAX), 512, 0, stream>>>(
        Hb, W2T, b2, (void*)Op, cnts, offs, ts);

    ln_combine_kernel<<<TOK, 256, 0, stream>>>(Op, x, topk_i, topk_w, inv_row, ln_g, ln_b, y);
}

// Round 17
// 720.494 us; speedup vs baseline: 1.7656x; 1.0469x over previous
//
#include <hip/hip_runtime.h>
#include <hip/hip_bf16.h>

#define TOK   8192      // B*S
#define HD    1024      // H
#define FD    4096      // F
#define NE    8         // E
#define TOPK  2
#define NPAIR (TOK*TOPK)   // 16384, fixed
#define PADR  128          // row padding for tile overrun
#define BM    128
#define BN    256
#define BK    32
#define TMAX  (NPAIR/BM + NE)   // 136 grid rows; nwg stays %8==0
#define CSTR  276               // C-staging LDS row stride (shorts)

typedef short bf16x8 __attribute__((ext_vector_type(8)));
typedef float f32x4  __attribute__((ext_vector_type(4)));

__device__ inline unsigned short f2bf(float f) {
    unsigned u = __float_as_uint(f);
    unsigned r = (u + 0x7fffu + ((u >> 16) & 1u)) >> 16;
    return (unsigned short)r;
}
__device__ inline float bf2f_lo(unsigned u) { return __uint_as_float((u & 0xffffu) << 16); }
__device__ inline float bf2f_hi(unsigned u) { return __uint_as_float(u & 0xffff0000u); }

// ---------------- merged transpose + fp32->bf16 convert for W1 and W2
template<int R, int C>
__device__ inline void transpose_tile(const float* __restrict__ in, short* __restrict__ out,
                                      float (*tile)[65], int cx, int ry, int e)
{
    const int tid = threadIdx.x;
    const int c0 = cx * 64, r0 = ry * 64;
    #pragma unroll
    for (int i = 0; i < 4; ++i) {
        int idx = i * 1024 + tid * 4;
        int rr = idx >> 6, cc = idx & 63;
        float4 v = *(const float4*)&in[((size_t)e * R + r0 + rr) * C + c0 + cc];
        tile[rr][cc] = v.x; tile[rr][cc + 1] = v.y;
        tile[rr][cc + 2] = v.z; tile[rr][cc + 3] = v.w;
    }
    __syncthreads();
    #pragma unroll
    for (int i = 0; i < 2; ++i) {
        int idx = i * 256 + tid;
        int cc = idx >> 3, rb = (idx & 7) * 8;
        uint4 w;
        w.x = (unsigned)f2bf(tile[rb + 0][cc]) | ((unsigned)f2bf(tile[rb + 1][cc]) << 16);
        w.y = (unsigned)f2bf(tile[rb + 2][cc]) | ((unsigned)f2bf(tile[rb + 3][cc]) << 16);
        w.z = (unsigned)f2bf(tile[rb + 4][cc]) | ((unsigned)f2bf(tile[rb + 5][cc]) << 16);
        w.w = (unsigned)f2bf(tile[rb + 6][cc]) | ((unsigned)f2bf(tile[rb + 7][cc]) << 16);
        *(uint4*)&out[((size_t)e * C + c0 + cc) * R + r0 + rb] = w;
    }
}

__global__ __launch_bounds__(256) void transpose_both_kernel(
    const float* __restrict__ W1, short* __restrict__ W1T,
    const float* __restrict__ W2, short* __restrict__ W2T)
{
    __shared__ float tile[64][65];
    int b = blockIdx.x;
    if (b < (FD / 64) * (HD / 64) * NE) {          // 8192 blocks for W1 [HD][FD]
        int e = b >> 10, r = b & 1023;
        transpose_tile<HD, FD>(W1, W1T, tile, r & 63, r >> 6, e);
    } else {                                       // 8192 blocks for W2 [FD][HD]
        b -= (FD / 64) * (HD / 64) * NE;
        int e = b >> 10, r = b & 1023;
        transpose_tile<FD, HD>(W2, W2T, tile, r & 15, r >> 4, e);
    }
}

// ---------------- gating: fp64 LN + logits + softmax + top-2 (one wave per token)
__global__ __launch_bounds__(256) void gating_kernel(
    const float* __restrict__ x, const float* __restrict__ gn_g, const float* __restrict__ gn_b,
    const float* __restrict__ gate_w, const float* __restrict__ gate_b,
    int* __restrict__ topk_i, float* __restrict__ topk_w, int* __restrict__ counts)
{
    const int wv = threadIdx.x >> 6, lane = threadIdx.x & 63;
    const int t = blockIdx.x * 4 + wv;
    const float* xr = x + (size_t)t * HD;

    double xs[16];
    #pragma unroll
    for (int i = 0; i < 16; ++i) xs[i] = (double)xr[i * 64 + lane];
    double s = 0.0;
    #pragma unroll
    for (int i = 0; i < 16; ++i) s += xs[i];
    #pragma unroll
    for (int o = 32; o > 0; o >>= 1) s += __shfl_xor(s, o, 64);
    double mean = s * (1.0 / HD);
    double ss = 0.0;
    #pragma unroll
    for (int i = 0; i < 16; ++i) { double d = xs[i] - mean; ss += d * d; }
    #pragma unroll
    for (int o = 32; o > 0; o >>= 1) ss += __shfl_xor(ss, o, 64);
    double inv = 1.0 / sqrt(ss * (1.0 / HD) + 1e-5);

    double ac[NE];
    #pragma unroll
    for (int e = 0; e < NE; ++e) ac[e] = 0.0;
    #pragma unroll
    for (int i = 0; i < 16; ++i) {
        int h = i * 64 + lane;
        double ln = (xs[i] - mean) * inv * (double)gn_g[h] + (double)gn_b[h];
        #pragma unroll
        for (int e = 0; e < NE; ++e) ac[e] += ln * (double)gate_w[h * NE + e];
    }
    #pragma unroll
    for (int e = 0; e < NE; ++e) {
        #pragma unroll
        for (int o = 32; o > 0; o >>= 1) ac[e] += __shfl_xor(ac[e], o, 64);
    }
    if (lane == 0) {
        double lg[NE], p[NE];
        double mx = -1e300;
        #pragma unroll
        for (int e = 0; e < NE; ++e) { lg[e] = ac[e] + (double)gate_b[e]; mx = lg[e] > mx ? lg[e] : mx; }
        double ps = 0.0;
        #pragma unroll
        for (int e = 0; e < NE; ++e) { p[e] = exp(lg[e] - mx); ps += p[e]; }
        #pragma unroll
        for (int e = 0; e < NE; ++e) p[e] /= ps;
        int i0 = 0;
        for (int e = 1; e < NE; ++e) if (p[e] > p[i0]) i0 = e;   // strict > keeps first (jax tie rule)
        int i1 = (i0 == 0) ? 1 : 0;
        for (int e = 0; e < NE; ++e) if (e != i0 && p[e] > p[i1]) i1 = e;
        double den = p[i0] + p[i1] + 1e-9;
        topk_i[t * 2] = i0; topk_i[t * 2 + 1] = i1;
        topk_w[t * 2] = (float)(p[i0] / den);
        topk_w[t * 2 + 1] = (float)(p[i1] / den);
        atomicAdd(&counts[i0], 1);
        atomicAdd(&counts[i1], 1);
    }
}

// ---------------- tiny prefix sums: row offsets + BM-row tile prefix
__global__ void offsets_kernel(const int* __restrict__ counts,
                               int* __restrict__ offs, int* __restrict__ ts)
{
    if (threadIdx.x == 0) {
        int s = 0, t = 0;
        for (int e = 0; e < NE; ++e) {
            offs[e] = s; ts[e] = t;
            s += counts[e];
            t += (counts[e] + BM - 1) / BM;
        }
        offs[NE] = s; ts[NE] = t;
    }
}

// ---------------- deterministic atomic-free binning: pass 1 = per-block histogram
__global__ __launch_bounds__(256) void hist_kernel(
    const int* __restrict__ topk_i, int* __restrict__ ghist)
{
    __shared__ int h[NE];
    const int b = blockIdx.x, tid = threadIdx.x;
    if (tid < NE) h[tid] = 0;
    __syncthreads();
    int e = topk_i[b * 256 + tid];
    atomicAdd(&h[e], 1);          // LDS atomic
    __syncthreads();
    if (tid < NE) ghist[b * NE + tid] = h[tid];
}

// pass 2: block base via prefix over ghist + stable within-block rank -> inv_row
__global__ __launch_bounds__(256) void scatter_kernel(
    const int* __restrict__ topk_i, const int* __restrict__ offs,
    const int* __restrict__ ghist, int* __restrict__ inv_row)
{
    __shared__ int baseS[NE];
    __shared__ unsigned char se[256];
    const int b = blockIdx.x, tid = threadIdx.x;
    const int idx = b * 256 + tid;
    const int e = topk_i[idx];
    if (tid < NE) {
        int s = offs[tid];
        for (int j = 0; j < b; ++j) s += ghist[j * NE + tid];
        baseS[tid] = s;
    }
    se[tid] = (unsigned char)e;
    __syncthreads();
    int rank = 0;
    for (int j = 0; j < tid; ++j) rank += (se[j] == (unsigned char)e);
    inv_row[idx] = baseS[e] + rank;
}

// ---------------- gather x rows (fp32) -> Xg (bf16, grouped order); 8 pairs/block
__global__ __launch_bounds__(256) void gather_kernel(
    const float* __restrict__ x, const int* __restrict__ inv_row, short* __restrict__ Xg)
{
    const int tid = threadIdx.x;
    #pragma unroll
    for (int i = 0; i < 8; ++i) {
        int p = blockIdx.x * 8 + i;
        int dst = inv_row[p];
        int t = p >> 1;
        float4 v = *(const float4*)&x[(size_t)t * HD + tid * 4];
        unsigned w0 = (unsigned)f2bf(v.x) | ((unsigned)f2bf(v.y) << 16);
        unsigned w1 = (unsigned)f2bf(v.z) | ((unsigned)f2bf(v.w) << 16);
        *(uint2*)&Xg[(size_t)dst * HD + tid * 4] = make_uint2(w0, w1);
    }
}

// counted-vmcnt boundary: allow N loads (per wave) to stay in flight, then barrier.
#define WAITB(n) do {                                                   \
    asm volatile("s_waitcnt vmcnt(" #n ")" ::: "memory");               \
    __builtin_amdgcn_s_barrier();                                       \
    __builtin_amdgcn_sched_barrier(0);                                  \
} while (0)

#define GLOAD(srcp, dstp) __builtin_amdgcn_global_load_lds(                         \
        (const __attribute__((address_space(1))) unsigned*)(srcp),                  \
        (__attribute__((address_space(3))) unsigned*)(dstp), 16, 0, 0)

// ---------------- grouped GEMM (r13 structure), LDS-staged bf16 C epilogue for
// BOTH outputs (512B uint4 segments; Smem reused after final barrier).
// EPI==1: +bias, gelu -> bf16 Hb ; EPI==2: +bias -> bf16 Op (both grouped rows)
template<int KDIM, int NDIM, int EPI>
__global__ __launch_bounds__(512, 4) void gemm_kernel(
    const short* __restrict__ A, const short* __restrict__ BT,
    const float* __restrict__ bias, short* __restrict__ outp,
    const int* __restrict__ counts, const int* __restrict__ offs,
    const int* __restrict__ ts)
{
    // bijective XCD swizzle (nwg % 8 == 0: 16*136=2176, 4*136=544)
    const int nwg = gridDim.x * gridDim.y;
    const int orig = blockIdx.y * gridDim.x + blockIdx.x;
    const int v = (orig & 7) * (nwg >> 3) + (orig >> 3);
    const int bx = v % gridDim.x;             // col tile
    const int j = v / gridDim.x;              // global row tile

    if (j >= ts[NE]) return;                  // inactive tail block (block-uniform)

    int e = 0;
    #pragma unroll
    for (int k = 1; k < NE; ++k) if (j >= ts[k]) e = k;
    const int cnt = counts[e];
    const int rt = j - ts[e];
    const int rowbase = offs[e] + rt * BM;
    const int colbase = bx * BN;

    const int tid = threadIdx.x;

    // 72 KB shared pool: K-loop = As(24KB) + Bs(48KB); epilogue reuses as C staging
    __shared__ __align__(16) short Smem[3 * BM * BK + 3 * BN * BK];
    short* As = Smem;
    short* Bs = Smem + 3 * BM * BK;

    const int lane = tid & 63;
    const int wv = tid >> 6;                  // 8 waves: 2 M-groups x 4 N-groups
    const int wr = (wv >> 2) * 64, wc = (wv & 3) * 64;
    const int l15 = lane & 15, l4 = lane >> 4;

    // staging: A = 4096 shorts (1 granule/thread), B = 8192 shorts (2 granules/thread)
    const int se0 = tid * 8;                  // LDS short index, rows 0..127
    const int sr0 = se0 >> 5;                 // staging row
    const int sg0 = (se0 >> 3) & 3;           // physical 16B granule within row
    const int sr1 = sr0 + 128;                // B pass 1 rows 128..255
    // pre-swizzled global k-offset: phys granule g holds global granule g^((r>>1)&3)
    const int sk0 = ((sg0 ^ ((sr0 >> 1) & 3)) << 3);
    const int sk1 = ((sg0 ^ ((sr1 >> 1) & 3)) << 3);

    // ds_read offsets: logical granule l4 of row r at phys g = l4^((r>>1)&3)
    int aoff[4], boff[4];
    #pragma unroll
    for (int m = 0; m < 4; ++m) {
        int r = wr + m * 16 + l15;
        aoff[m] = r * BK + ((l4 ^ ((r >> 1) & 3)) << 3);
    }
    #pragma unroll
    for (int n = 0; n < 4; ++n) {
        int r = wc + n * 16 + l15;
        boff[n] = r * BK + ((l4 ^ ((r >> 1) & 3)) << 3);
    }

    const size_t bbase = (size_t)e * NDIM + colbase;

#define STAGE(sl, k0) do {                                                                \
        short* asl = &As[(sl) * (BM * BK)];                                               \
        short* bsl = &Bs[(sl) * (BN * BK)];                                               \
        const short* a0s = A + (size_t)(rowbase + sr0) * KDIM + (k0) + sk0;               \
        GLOAD(a0s, &asl[se0]);                                                            \
        const short* b0s = BT + (bbase + sr0) * KDIM + (k0) + sk0;                        \
        GLOAD(b0s, &bsl[se0]);                                                            \
        const short* b1s = BT + (bbase + sr1) * KDIM + (k0) + sk1;                        \
        GLOAD(b1s, &bsl[se0 + 4096]);                                                     \
    } while (0)

    constexpr int NT = KDIM / BK;

    // prologue: stage tiles 0 and 1; wait tile 0 (allow tile 1's 3 loads in flight)
    STAGE(0, 0);
    STAGE(1, BK);
    WAITB(3);

    f32x4 acc[4][4];
    #pragma unroll
    for (int m = 0; m < 4; ++m)
        #pragma unroll
        for (int n = 0; n < 4; ++n)
            acc[m][n] = (f32x4){0.f, 0.f, 0.f, 0.f};

    for (int t = 0; t < NT; ++t) {
        if (t + 2 < NT) STAGE((t + 2) % 3, (t + 2) * BK);   // 2-K-tile prefetch

        const short* asl = &As[(t % 3) * (BM * BK)];
        const short* bsl = &Bs[(t % 3) * (BN * BK)];
        bf16x8 a[4], b[4];
        #pragma unroll
        for (int m = 0; m < 4; ++m)
            a[m] = *(const bf16x8*)&asl[aoff[m]];
        #pragma unroll
        for (int n = 0; n < 4; ++n)
            b[n] = *(const bf16x8*)&bsl[boff[n]];

        __builtin_amdgcn_s_setprio(1);
        #pragma unroll
        for (int m = 0; m < 4; ++m)
            #pragma unroll
            for (int n = 0; n < 4; ++n)
                acc[m][n] = __builtin_amdgcn_mfma_f32_16x16x32_bf16(a[m], b[n], acc[m][n], 0, 0, 0);
        __builtin_amdgcn_s_setprio(0);

        if (t < NT - 1) {
            if (t == NT - 2) WAITB(0); else WAITB(3);
        }
    }
#undef STAGE

    const int rmax = cnt - rt * BM;   // valid rows in this tile (tail tiles < BM)

    __syncthreads();              // all waves done reading As/Bs -> reuse as C staging
    short* Cs = Smem;             // [128][CSTR] shorts
    #pragma unroll
    for (int n = 0; n < 4; ++n) {
        int col = wc + n * 16 + l15;
        float bv = bias[e * NDIM + colbase + col];
        #pragma unroll
        for (int m = 0; m < 4; ++m) {
            int r0l = wr + m * 16 + l4 * 4;
            #pragma unroll
            for (int r = 0; r < 4; ++r) {
                float vv = acc[m][n][r] + bv;
                if (EPI == 1)
                    vv = 0.5f * vv * (1.0f + erff(vv * 0.70710678118654752f));
                Cs[(r0l + r) * CSTR + col] = (short)f2bf(vv);
            }
        }
    }
    __syncthreads();
    // copy out: 8 iters x 512 threads x 16B; row = i*16 + (tid>>5), col = (tid&31)*8
    const int crow0 = tid >> 5, ccol = (tid & 31) * 8;
    #pragma unroll
    for (int i = 0; i < 8; ++i) {
        int row = i * 16 + crow0;
        if (row < rmax) {
            const short* src = &Cs[row * CSTR + ccol];
            *(uint4*)&outp[(size_t)(rowbase + row) * NDIM + colbase + ccol] =
                *(const uint4*)src;
        }
    }
}

// ---------------- residual + LN + weighted top-k combine; one WAVE per token,
// shuffle-only reductions (no block barriers); Op is bf16 grouped rows.
__global__ __launch_bounds__(256) void ln_combine_kernel(
    const short* __restrict__ Op, const float* __restrict__ x,
    const int* __restrict__ topk_i, const float* __restrict__ topk_w,
    const int* __restrict__ inv_row,
    const float* __restrict__ ln_g, const float* __restrict__ ln_b,
    float* __restrict__ y)
{
    const int wvi = threadIdx.x >> 6, lane = threadIdx.x & 63;
    const int t = blockIdx.x * 4 + wvi;

    float4 xv[4];
    #pragma unroll
    for (int i = 0; i < 4; ++i)
        xv[i] = *(const float4*)&x[(size_t)t * HD + (lane + i * 64) * 4];

    float a[16];
    #pragma unroll
    for (int i = 0; i < 16; ++i) a[i] = 0.f;

    #pragma unroll
    for (int k = 0; k < TOPK; ++k) {
        const int e = topk_i[t * 2 + k];
        const float w = topk_w[t * 2 + k];
        const int grow = inv_row[t * 2 + k];

        float vbuf[16];
        float s = 0.f;
        #pragma unroll
        for (int i = 0; i < 4; ++i) {
            uint2 ov = *(const uint2*)&Op[(size_t)grow * HD + (lane + i * 64) * 4];
            float v0 = bf2f_lo(ov.x) + xv[i].x;
            float v1 = bf2f_hi(ov.x) + xv[i].y;
            float v2 = bf2f_lo(ov.y) + xv[i].z;
            float v3 = bf2f_hi(ov.y) + xv[i].w;
            vbuf[i * 4 + 0] = v0; vbuf[i * 4 + 1] = v1;
            vbuf[i * 4 + 2] = v2; vbuf[i * 4 + 3] = v3;
            s += (v0 + v1) + (v2 + v3);
        }
        #pragma unroll
        for (int o = 32; o > 0; o >>= 1) s += __shfl_xor(s, o, 64);
        const float m = s * (1.0f / HD);
        float ssq = 0.f;
        #pragma unroll
        for (int i = 0; i < 16; ++i) { float d = vbuf[i] - m; vbuf[i] = d; ssq += d * d; }
        #pragma unroll
        for (int o = 32; o > 0; o >>= 1) ssq += __shfl_xor(ssq, o, 64);
        const float inv = 1.0f / sqrtf(ssq * (1.0f / HD) + 1e-5f);

        #pragma unroll
        for (int i = 0; i < 4; ++i) {
            int base = e * HD + (lane + i * 64) * 4;
            const float4 g = *(const float4*)&ln_g[base];
            const float4 bb = *(const float4*)&ln_b[base];
            a[i * 4 + 0] += w * (vbuf[i * 4 + 0] * inv * g.x + bb.x);
            a[i * 4 + 1] += w * (vbuf[i * 4 + 1] * inv * g.y + bb.y);
            a[i * 4 + 2] += w * (vbuf[i * 4 + 2] * inv * g.z + bb.z);
            a[i * 4 + 3] += w * (vbuf[i * 4 + 3] * inv * g.w + bb.w);
        }
    }
    #pragma unroll
    for (int i = 0; i < 4; ++i)
        *(float4*)&y[(size_t)t * HD + (lane + i * 64) * 4] =
            make_float4(a[i * 4 + 0], a[i * 4 + 1], a[i * 4 + 2], a[i * 4 + 3]);
}

__global__ void zero_out_kernel(float* __restrict__ y, int n)
{
    int i = blockIdx.x * 256 + threadIdx.x;
    if (i < n) y[i] = 0.f;
}

extern "C" void kernel_launch(void* const* d_in, const int* in_sizes, int n_in,
                              void* d_out, int out_size, void* d_ws, size_t ws_size,
                              hipStream_t stream)
{
    const float* x      = (const float*)d_in[0];
    const float* W1     = (const float*)d_in[1];
    const float* b1     = (const float*)d_in[2];
    const float* W2     = (const float*)d_in[3];
    const float* b2     = (const float*)d_in[4];
    const float* ln_g   = (const float*)d_in[5];
    const float* ln_b   = (const float*)d_in[6];
    const float* gn_g   = (const float*)d_in[7];
    const float* gn_b   = (const float*)d_in[8];
    const float* gate_w = (const float*)d_in[9];
    const float* gate_b = (const float*)d_in[10];
    float* y = (float*)d_out;

    char* ws = (char*)d_ws;
    size_t off = 0;
    auto take = [&](size_t b) -> char* {
        char* p = ws + off;
        off = (off + b + 255) & ~(size_t)255;
        return p;
    };
    short* W1T     = (short*)take((size_t)NE * FD * HD * 2);       // [E][F][H] bf16
    short* W2T     = (short*)take((size_t)NE * HD * FD * 2);       // [E][H][F] bf16
    short* Xg      = (short*)take((size_t)(NPAIR + PADR) * HD * 2);
    short* Hb      = (short*)take((size_t)(NPAIR + PADR) * FD * 2);
    short* Op      = (short*)take((size_t)(NPAIR + PADR) * HD * 2);// bf16 grouped rows
    int*   topk_i  = (int*)take(NPAIR * 4);
    float* topk_w  = (float*)take(NPAIR * 4);
    int*   cnts    = (int*)take(64);
    int*   offs    = (int*)take(64);
    int*   ts      = (int*)take(64);            // tile prefix (BM=128)
    int*   ghist   = (int*)take(64 * NE * 4);   // per-block histograms
    int*   inv_row = (int*)take((size_t)NPAIR * 4);

    if (ws_size < off) {   // workspace too small: emit zeros so failure mode is diagnosable
        zero_out_kernel<<<(out_size + 255) / 256, 256, 0, stream>>>(y, out_size);
        return;
    }

    hipMemsetAsync(cnts, 0, 64, stream);

    transpose_both_kernel<<<2 * (FD / 64) * (HD / 64) * NE, 256, 0, stream>>>(W1, W1T, W2, W2T);

    gating_kernel<<<TOK / 4, 256, 0, stream>>>(x, gn_g, gn_b, gate_w, gate_b, topk_i, topk_w, cnts);
    offsets_kernel<<<1, 64, 0, stream>>>(cnts, offs, ts);
    hist_kernel<<<NPAIR / 256, 256, 0, stream>>>(topk_i, ghist);
    scatter_kernel<<<NPAIR / 256, 256, 0, stream>>>(topk_i, offs, ghist, inv_row);
    gather_kernel<<<NPAIR / 8, 256, 0, stream>>>(x, inv_row, Xg);

    // Flat-tile balanced grouped GEMMs (r13 config, LDS-staged bf16 epilogues).
    gemm_kernel<HD, FD, 1><<<dim3(FD / BN, TMAX), 512, 0, stream>>>(
        Xg, W1T, b1, Hb, cnts, offs, ts);
    gemm_kernel<FD, HD, 2><<<dim3(HD / BN, TMAX), 512, 0, stream>>>(
        Hb, W2T, b2, Op, cnts, offs, ts);

    ln_combine_kernel<<<TOK / 4, 256, 0, stream>>>(Op, x, topk_i, topk_w, inv_row, ln_g, ln_b, y);
}

// Round 18
// 711.126 us; speedup vs baseline: 1.7889x; 1.0132x over previous
//
#include <hip/hip_runtime.h>
#include <hip/hip_bf16.h>

#define TOK   8192      // B*S
#define HD    1024      // H
#define FD    4096      // F
#define NE    8         // E
#define TOPK  2
#define NPAIR (TOK*TOPK)   // 16384, fixed
#define PADR  128          // row padding for tile overrun
#define BM    128
#define BN    256
#define BK    32
#define TMAX  (NPAIR/BM + NE)   // 136 grid rows; nwg stays %8==0
#define CSTR  276               // C-staging LDS row stride (shorts)

typedef short bf16x8 __attribute__((ext_vector_type(8)));
typedef float f32x4  __attribute__((ext_vector_type(4)));

__device__ inline unsigned short f2bf(float f) {
    unsigned u = __float_as_uint(f);
    unsigned r = (u + 0x7fffu + ((u >> 16) & 1u)) >> 16;
    return (unsigned short)r;
}
__device__ inline float bf2f_lo(unsigned u) { return __uint_as_float((u & 0xffffu) << 16); }
__device__ inline float bf2f_hi(unsigned u) { return __uint_as_float(u & 0xffff0000u); }

// ---------------- merged transpose + fp32->bf16 convert for W1 and W2
template<int R, int C>
__device__ inline void transpose_tile(const float* __restrict__ in, short* __restrict__ out,
                                      float (*tile)[65], int cx, int ry, int e)
{
    const int tid = threadIdx.x;
    const int c0 = cx * 64, r0 = ry * 64;
    #pragma unroll
    for (int i = 0; i < 4; ++i) {
        int idx = i * 1024 + tid * 4;
        int rr = idx >> 6, cc = idx & 63;
        float4 v = *(const float4*)&in[((size_t)e * R + r0 + rr) * C + c0 + cc];
        tile[rr][cc] = v.x; tile[rr][cc + 1] = v.y;
        tile[rr][cc + 2] = v.z; tile[rr][cc + 3] = v.w;
    }
    __syncthreads();
    #pragma unroll
    for (int i = 0; i < 2; ++i) {
        int idx = i * 256 + tid;
        int cc = idx >> 3, rb = (idx & 7) * 8;
        uint4 w;
        w.x = (unsigned)f2bf(tile[rb + 0][cc]) | ((unsigned)f2bf(tile[rb + 1][cc]) << 16);
        w.y = (unsigned)f2bf(tile[rb + 2][cc]) | ((unsigned)f2bf(tile[rb + 3][cc]) << 16);
        w.z = (unsigned)f2bf(tile[rb + 4][cc]) | ((unsigned)f2bf(tile[rb + 5][cc]) << 16);
        w.w = (unsigned)f2bf(tile[rb + 6][cc]) | ((unsigned)f2bf(tile[rb + 7][cc]) << 16);
        *(uint4*)&out[((size_t)e * C + c0 + cc) * R + r0 + rb] = w;
    }
}

__global__ __launch_bounds__(256) void transpose_both_kernel(
    const float* __restrict__ W1, short* __restrict__ W1T,
    const float* __restrict__ W2, short* __restrict__ W2T)
{
    __shared__ float tile[64][65];
    int b = blockIdx.x;
    if (b < (FD / 64) * (HD / 64) * NE) {          // 8192 blocks for W1 [HD][FD]
        int e = b >> 10, r = b & 1023;
        transpose_tile<HD, FD>(W1, W1T, tile, r & 63, r >> 6, e);
    } else {                                       // 8192 blocks for W2 [FD][HD]
        b -= (FD / 64) * (HD / 64) * NE;
        int e = b >> 10, r = b & 1023;
        transpose_tile<FD, HD>(W2, W2T, tile, r & 15, r >> 4, e);
    }
}

// ---------------- gating: fp64 LN + logits + softmax + top-2 (one wave per token)
// also emits per-expert rank (atomicAdd return) for offset-free grouping
__global__ __launch_bounds__(256) void gating_kernel(
    const float* __restrict__ x, const float* __restrict__ gn_g, const float* __restrict__ gn_b,
    const float* __restrict__ gate_w, const float* __restrict__ gate_b,
    int* __restrict__ topk_i, float* __restrict__ topk_w,
    int* __restrict__ rank, int* __restrict__ counts)
{
    const int wv = threadIdx.x >> 6, lane = threadIdx.x & 63;
    const int t = blockIdx.x * 4 + wv;
    const float* xr = x + (size_t)t * HD;

    double xs[16];
    #pragma unroll
    for (int i = 0; i < 16; ++i) xs[i] = (double)xr[i * 64 + lane];
    double s = 0.0;
    #pragma unroll
    for (int i = 0; i < 16; ++i) s += xs[i];
    #pragma unroll
    for (int o = 32; o > 0; o >>= 1) s += __shfl_xor(s, o, 64);
    double mean = s * (1.0 / HD);
    double ss = 0.0;
    #pragma unroll
    for (int i = 0; i < 16; ++i) { double d = xs[i] - mean; ss += d * d; }
    #pragma unroll
    for (int o = 32; o > 0; o >>= 1) ss += __shfl_xor(ss, o, 64);
    double inv = 1.0 / sqrt(ss * (1.0 / HD) + 1e-5);

    double ac[NE];
    #pragma unroll
    for (int e = 0; e < NE; ++e) ac[e] = 0.0;
    #pragma unroll
    for (int i = 0; i < 16; ++i) {
        int h = i * 64 + lane;
        double ln = (xs[i] - mean) * inv * (double)gn_g[h] + (double)gn_b[h];
        #pragma unroll
        for (int e = 0; e < NE; ++e) ac[e] += ln * (double)gate_w[h * NE + e];
    }
    #pragma unroll
    for (int e = 0; e < NE; ++e) {
        #pragma unroll
        for (int o = 32; o > 0; o >>= 1) ac[e] += __shfl_xor(ac[e], o, 64);
    }
    if (lane == 0) {
        double lg[NE], p[NE];
        double mx = -1e300;
        #pragma unroll
        for (int e = 0; e < NE; ++e) { lg[e] = ac[e] + (double)gate_b[e]; mx = lg[e] > mx ? lg[e] : mx; }
        double ps = 0.0;
        #pragma unroll
        for (int e = 0; e < NE; ++e) { p[e] = exp(lg[e] - mx); ps += p[e]; }
        #pragma unroll
        for (int e = 0; e < NE; ++e) p[e] /= ps;
        int i0 = 0;
        for (int e = 1; e < NE; ++e) if (p[e] > p[i0]) i0 = e;   // strict > keeps first (jax tie rule)
        int i1 = (i0 == 0) ? 1 : 0;
        for (int e = 0; e < NE; ++e) if (e != i0 && p[e] > p[i1]) i1 = e;
        double den = p[i0] + p[i1] + 1e-9;
        topk_i[t * 2] = i0; topk_i[t * 2 + 1] = i1;
        topk_w[t * 2] = (float)(p[i0] / den);
        topk_w[t * 2 + 1] = (float)(p[i1] / den);
        rank[t * 2]     = atomicAdd(&counts[i0], 1);
        rank[t * 2 + 1] = atomicAdd(&counts[i1], 1);
    }
}

// ---------------- gather x rows (fp32) -> Xg (bf16, grouped order); 8 pairs/block.
// offs computed inline from counts (8 uniform loads); writes inv_row for ln_combine.
__global__ __launch_bounds__(256) void gather_kernel(
    const float* __restrict__ x, const int* __restrict__ topk_i,
    const int* __restrict__ rank, const int* __restrict__ counts,
    int* __restrict__ inv_row, short* __restrict__ Xg)
{
    const int tid = threadIdx.x;
    int offv[NE];
    {
        int s = 0;
        #pragma unroll
        for (int k = 0; k < NE; ++k) { offv[k] = s; s += counts[k]; }
    }
    #pragma unroll
    for (int i = 0; i < 8; ++i) {
        int p = blockIdx.x * 8 + i;
        int e = topk_i[p];
        int dst = offv[e] + rank[p];
        if (tid == 0) inv_row[p] = dst;
        int t = p >> 1;
        float4 v = *(const float4*)&x[(size_t)t * HD + tid * 4];
        unsigned w0 = (unsigned)f2bf(v.x) | ((unsigned)f2bf(v.y) << 16);
        unsigned w1 = (unsigned)f2bf(v.z) | ((unsigned)f2bf(v.w) << 16);
        *(uint2*)&Xg[(size_t)dst * HD + tid * 4] = make_uint2(w0, w1);
    }
}

// counted-vmcnt boundary: allow N loads (per wave) to stay in flight, then barrier.
#define WAITB(n) do {                                                   \
    asm volatile("s_waitcnt vmcnt(" #n ")" ::: "memory");               \
    __builtin_amdgcn_s_barrier();                                       \
    __builtin_amdgcn_sched_barrier(0);                                  \
} while (0)

#define GLOAD(srcp, dstp) __builtin_amdgcn_global_load_lds(                         \
        (const __attribute__((address_space(1))) unsigned*)(srcp),                  \
        (__attribute__((address_space(3))) unsigned*)(dstp), 16, 0, 0)

// ---------------- grouped GEMM (r13 structure), LDS-staged bf16 C epilogue.
// offs/ts computed inline from counts (prefix over 8).
// EPI==1: +bias, gelu -> bf16 Hb ; EPI==2: +bias -> bf16 Op (both grouped rows)
template<int KDIM, int NDIM, int EPI>
__global__ __launch_bounds__(512, 4) void gemm_kernel(
    const short* __restrict__ A, const short* __restrict__ BT,
    const float* __restrict__ bias, short* __restrict__ outp,
    const int* __restrict__ counts)
{
    // bijective XCD swizzle (nwg % 8 == 0: 16*136=2176, 4*136=544)
    const int nwg = gridDim.x * gridDim.y;
    const int orig = blockIdx.y * gridDim.x + blockIdx.x;
    const int v = (orig & 7) * (nwg >> 3) + (orig >> 3);
    const int bx = v % gridDim.x;             // col tile
    const int j = v / gridDim.x;              // global row tile

    // inline offs/ts prefix over counts
    int e = -1, rowbase = 0, rt = 0, cnt = 0;
    {
        int s = 0, t = 0;
        #pragma unroll
        for (int k = 0; k < NE; ++k) {
            int c = counts[k];
            int nt = (c + BM - 1) >> 7;       // BM = 128
            if (e < 0 && j >= t && j < t + nt) {
                e = k; rt = j - t; rowbase = s + rt * BM; cnt = c;
            }
            s += c; t += nt;
        }
    }
    if (e < 0) return;                        // inactive tail block (block-uniform)

    const int colbase = bx * BN;
    const int tid = threadIdx.x;

    // 72 KB shared pool: K-loop = As(24KB) + Bs(48KB); epilogue reuses as C staging
    __shared__ __align__(16) short Smem[3 * BM * BK + 3 * BN * BK];
    short* As = Smem;
    short* Bs = Smem + 3 * BM * BK;

    const int lane = tid & 63;
    const int wv = tid >> 6;                  // 8 waves: 2 M-groups x 4 N-groups
    const int wr = (wv >> 2) * 64, wc = (wv & 3) * 64;
    const int l15 = lane & 15, l4 = lane >> 4;

    // staging: A = 4096 shorts (1 granule/thread), B = 8192 shorts (2 granules/thread)
    const int se0 = tid * 8;                  // LDS short index, rows 0..127
    const int sr0 = se0 >> 5;                 // staging row
    const int sg0 = (se0 >> 3) & 3;           // physical 16B granule within row
    const int sr1 = sr0 + 128;                // B pass 1 rows 128..255
    // pre-swizzled global k-offset: phys granule g holds global granule g^((r>>1)&3)
    const int sk0 = ((sg0 ^ ((sr0 >> 1) & 3)) << 3);
    const int sk1 = ((sg0 ^ ((sr1 >> 1) & 3)) << 3);

    // ds_read offsets: logical granule l4 of row r at phys g = l4^((r>>1)&3)
    int aoff[4], boff[4];
    #pragma unroll
    for (int m = 0; m < 4; ++m) {
        int r = wr + m * 16 + l15;
        aoff[m] = r * BK + ((l4 ^ ((r >> 1) & 3)) << 3);
    }
    #pragma unroll
    for (int n = 0; n < 4; ++n) {
        int r = wc + n * 16 + l15;
        boff[n] = r * BK + ((l4 ^ ((r >> 1) & 3)) << 3);
    }

    const size_t bbase = (size_t)e * NDIM + colbase;

#define STAGE(sl, k0) do {                                                                \
        short* asl = &As[(sl) * (BM * BK)];                                               \
        short* bsl = &Bs[(sl) * (BN * BK)];                                               \
        const short* a0s = A + (size_t)(rowbase + sr0) * KDIM + (k0) + sk0;               \
        GLOAD(a0s, &asl[se0]);                                                            \
        const short* b0s = BT + (bbase + sr0) * KDIM + (k0) + sk0;                        \
        GLOAD(b0s, &bsl[se0]);                                                            \
        const short* b1s = BT + (bbase + sr1) * KDIM + (k0) + sk1;                        \
        GLOAD(b1s, &bsl[se0 + 4096]);                                                     \
    } while (0)

    constexpr int NT = KDIM / BK;

    // prologue: stage tiles 0 and 1; wait tile 0 (allow tile 1's 3 loads in flight)
    STAGE(0, 0);
    STAGE(1, BK);
    WAITB(3);

    f32x4 acc[4][4];
    #pragma unroll
    for (int m = 0; m < 4; ++m)
        #pragma unroll
        for (int n = 0; n < 4; ++n)
            acc[m][n] = (f32x4){0.f, 0.f, 0.f, 0.f};

    for (int t = 0; t < NT; ++t) {
        if (t + 2 < NT) STAGE((t + 2) % 3, (t + 2) * BK);   // 2-K-tile prefetch

        const short* asl = &As[(t % 3) * (BM * BK)];
        const short* bsl = &Bs[(t % 3) * (BN * BK)];
        bf16x8 a[4], b[4];
        #pragma unroll
        for (int m = 0; m < 4; ++m)
            a[m] = *(const bf16x8*)&asl[aoff[m]];
        #pragma unroll
        for (int n = 0; n < 4; ++n)
            b[n] = *(const bf16x8*)&bsl[boff[n]];

        __builtin_amdgcn_s_setprio(1);
        #pragma unroll
        for (int m = 0; m < 4; ++m)
            #pragma unroll
            for (int n = 0; n < 4; ++n)
                acc[m][n] = __builtin_amdgcn_mfma_f32_16x16x32_bf16(a[m], b[n], acc[m][n], 0, 0, 0);
        __builtin_amdgcn_s_setprio(0);

        if (t < NT - 1) {
            if (t == NT - 2) WAITB(0); else WAITB(3);
        }
    }
#undef STAGE

    const int rmax = cnt - rt * BM;   // valid rows in this tile (tail tiles < BM)

    __syncthreads();              // all waves done reading As/Bs -> reuse as C staging
    short* Cs = Smem;             // [128][CSTR] shorts
    #pragma unroll
    for (int n = 0; n < 4; ++n) {
        int col = wc + n * 16 + l15;
        float bv = bias[e * NDIM + colbase + col];
        #pragma unroll
        for (int m = 0; m < 4; ++m) {
            int r0l = wr + m * 16 + l4 * 4;
            #pragma unroll
            for (int r = 0; r < 4; ++r) {
                float vv = acc[m][n][r] + bv;
                if (EPI == 1)
                    vv = 0.5f * vv * (1.0f + erff(vv * 0.70710678118654752f));
                Cs[(r0l + r) * CSTR + col] = (short)f2bf(vv);
            }
        }
    }
    __syncthreads();
    // copy out: 8 iters x 512 threads x 16B; row = i*16 + (tid>>5), col = (tid&31)*8
    const int crow0 = tid >> 5, ccol = (tid & 31) * 8;
    #pragma unroll
    for (int i = 0; i < 8; ++i) {
        int row = i * 16 + crow0;
        if (row < rmax) {
            const short* src = &Cs[row * CSTR + ccol];
            *(uint4*)&outp[(size_t)(rowbase + row) * NDIM + colbase + ccol] =
                *(const uint4*)src;
        }
    }
}

// ---------------- residual + LN + weighted top-k combine; one WAVE per token,
// shuffle-only reductions; Op is bf16 grouped rows.
__global__ __launch_bounds__(256) void ln_combine_kernel(
    const short* __restrict__ Op, const float* __restrict__ x,
    const int* __restrict__ topk_i, const float* __restrict__ topk_w,
    const int* __restrict__ inv_row,
    const float* __restrict__ ln_g, const float* __restrict__ ln_b,
    float* __restrict__ y)
{
    const int wvi = threadIdx.x >> 6, lane = threadIdx.x & 63;
    const int t = blockIdx.x * 4 + wvi;

    float4 xv[4];
    #pragma unroll
    for (int i = 0; i < 4; ++i)
        xv[i] = *(const float4*)&x[(size_t)t * HD + (lane + i * 64) * 4];

    float a[16];
    #pragma unroll
    for (int i = 0; i < 16; ++i) a[i] = 0.f;

    #pragma unroll
    for (int k = 0; k < TOPK; ++k) {
        const int e = topk_i[t * 2 + k];
        const float w = topk_w[t * 2 + k];
        const int grow = inv_row[t * 2 + k];

        float vbuf[16];
        float s = 0.f;
        #pragma unroll
        for (int i = 0; i < 4; ++i) {
            uint2 ov = *(const uint2*)&Op[(size_t)grow * HD + (lane + i * 64) * 4];
            float v0 = bf2f_lo(ov.x) + xv[i].x;
            float v1 = bf2f_hi(ov.x) + xv[i].y;
            float v2 = bf2f_lo(ov.y) + xv[i].z;
            float v3 = bf2f_hi(ov.y) + xv[i].w;
            vbuf[i * 4 + 0] = v0; vbuf[i * 4 + 1] = v1;
            vbuf[i * 4 + 2] = v2; vbuf[i * 4 + 3] = v3;
            s += (v0 + v1) + (v2 + v3);
        }
        #pragma unroll
        for (int o = 32; o > 0; o >>= 1) s += __shfl_xor(s, o, 64);
        const float m = s * (1.0f / HD);
        float ssq = 0.f;
        #pragma unroll
        for (int i = 0; i < 16; ++i) { float d = vbuf[i] - m; vbuf[i] = d; ssq += d * d; }
        #pragma unroll
        for (int o = 32; o > 0; o >>= 1) ssq += __shfl_xor(ssq, o, 64);
        const float inv = 1.0f / sqrtf(ssq * (1.0f / HD) + 1e-5f);

        #pragma unroll
        for (int i = 0; i < 4; ++i) {
            int base = e * HD + (lane + i * 64) * 4;
            const float4 g = *(const float4*)&ln_g[base];
            const float4 bb = *(const float4*)&ln_b[base];
            a[i * 4 + 0] += w * (vbuf[i * 4 + 0] * inv * g.x + bb.x);
            a[i * 4 + 1] += w * (vbuf[i * 4 + 1] * inv * g.y + bb.y);
            a[i * 4 + 2] += w * (vbuf[i * 4 + 2] * inv * g.z + bb.z);
            a[i * 4 + 3] += w * (vbuf[i * 4 + 3] * inv * g.w + bb.w);
        }
    }
    #pragma unroll
    for (int i = 0; i < 4; ++i)
        *(float4*)&y[(size_t)t * HD + (lane + i * 64) * 4] =
            make_float4(a[i * 4 + 0], a[i * 4 + 1], a[i * 4 + 2], a[i * 4 + 3]);
}

__global__ void zero_out_kernel(float* __restrict__ y, int n)
{
    int i = blockIdx.x * 256 + threadIdx.x;
    if (i < n) y[i] = 0.f;
}

extern "C" void kernel_launch(void* const* d_in, const int* in_sizes, int n_in,
                              void* d_out, int out_size, void* d_ws, size_t ws_size,
                              hipStream_t stream)
{
    const float* x      = (const float*)d_in[0];
    const float* W1     = (const float*)d_in[1];
    const float* b1     = (const float*)d_in[2];
    const float* W2     = (const float*)d_in[3];
    const float* b2     = (const float*)d_in[4];
    const float* ln_g   = (const float*)d_in[5];
    const float* ln_b   = (const float*)d_in[6];
    const float* gn_g   = (const float*)d_in[7];
    const float* gn_b   = (const float*)d_in[8];
    const float* gate_w = (const float*)d_in[9];
    const float* gate_b = (const float*)d_in[10];
    float* y = (float*)d_out;

    char* ws = (char*)d_ws;
    size_t off = 0;
    auto take = [&](size_t b) -> char* {
        char* p = ws + off;
        off = (off + b + 255) & ~(size_t)255;
        return p;
    };
    short* W1T     = (short*)take((size_t)NE * FD * HD * 2);       // [E][F][H] bf16
    short* W2T     = (short*)take((size_t)NE * HD * FD * 2);       // [E][H][F] bf16
    short* Xg      = (short*)take((size_t)(NPAIR + PADR) * HD * 2);
    short* Hb      = (short*)take((size_t)(NPAIR + PADR) * FD * 2);
    short* Op      = (short*)take((size_t)(NPAIR + PADR) * HD * 2);// bf16 grouped rows
    int*   topk_i  = (int*)take(NPAIR * 4);
    float* topk_w  = (float*)take(NPAIR * 4);
    int*   rank    = (int*)take(NPAIR * 4);
    int*   cnts    = (int*)take(64);
    int*   inv_row = (int*)take((size_t)NPAIR * 4);

    if (ws_size < off) {   // workspace too small: emit zeros so failure mode is diagnosable
        zero_out_kernel<<<(out_size + 255) / 256, 256, 0, stream>>>(y, out_size);
        return;
    }

    hipMemsetAsync(cnts, 0, 64, stream);

    transpose_both_kernel<<<2 * (FD / 64) * (HD / 64) * NE, 256, 0, stream>>>(W1, W1T, W2, W2T);

    gating_kernel<<<TOK / 4, 256, 0, stream>>>(x, gn_g, gn_b, gate_w, gate_b,
                                               topk_i, topk_w, rank, cnts);
    gather_kernel<<<NPAIR / 8, 256, 0, stream>>>(x, topk_i, rank, cnts, inv_row, Xg);

    // Flat-tile balanced grouped GEMMs (r13 config, LDS-staged bf16 epilogues,
    // inline offs/ts from counts).
    gemm_kernel<HD, FD, 1><<<dim3(FD / BN, TMAX), 512, 0, stream>>>(
        Xg, W1T, b1, Hb, cnts);
    gemm_kernel<FD, HD, 2><<<dim3(HD / BN, TMAX), 512, 0, stream>>>(
        Hb, W2T, b2, Op, cnts);

    ln_combine_kernel<<<TOK / 4, 256, 0, stream>>>(Op, x, topk_i, topk_w, inv_row, ln_g, ln_b, y);
}

// Round 20
// 554.294 us; speedup vs baseline: 2.2950x; 1.2829x over previous
//
#include <hip/hip_runtime.h>
#include <hip/hip_bf16.h>

#define TOK   8192      // B*S
#define HD    1024      // H
#define FD    4096      // F
#define NE    8         // E
#define TOPK  2
#define NPAIR (TOK*TOPK)   // 16384, fixed
#define PADR  128          // row padding for tile overrun
#define BM    128
#define BN    256
#define BK    32
#define TMAX  (NPAIR/BM + NE)   // 136 grid rows; nwg stays %8==0
#define CSTR  276               // C-staging LDS row stride (shorts)
#define CNTS  32                // counter stride in ints (128 B -> one L2 line each)

typedef short bf16x8 __attribute__((ext_vector_type(8)));
typedef float f32x4  __attribute__((ext_vector_type(4)));

__device__ inline unsigned short f2bf(float f) {
    unsigned u = __float_as_uint(f);
    unsigned r = (u + 0x7fffu + ((u >> 16) & 1u)) >> 16;
    return (unsigned short)r;
}
__device__ inline float bf2f_lo(unsigned u) { return __uint_as_float((u & 0xffffu) << 16); }
__device__ inline float bf2f_hi(unsigned u) { return __uint_as_float(u & 0xffff0000u); }

// ---------------- merged transpose + fp32->bf16 convert for W1 and W2
template<int R, int C>
__device__ inline void transpose_tile(const float* __restrict__ in, short* __restrict__ out,
                                      float (*tile)[65], int cx, int ry, int e)
{
    const int tid = threadIdx.x;
    const int c0 = cx * 64, r0 = ry * 64;
    #pragma unroll
    for (int i = 0; i < 4; ++i) {
        int idx = i * 1024 + tid * 4;
        int rr = idx >> 6, cc = idx & 63;
        float4 v = *(const float4*)&in[((size_t)e * R + r0 + rr) * C + c0 + cc];
        tile[rr][cc] = v.x; tile[rr][cc + 1] = v.y;
        tile[rr][cc + 2] = v.z; tile[rr][cc + 3] = v.w;
    }
    __syncthreads();
    #pragma unroll
    for (int i = 0; i < 2; ++i) {
        int idx = i * 256 + tid;
        int cc = idx >> 3, rb = (idx & 7) * 8;
        uint4 w;
        w.x = (unsigned)f2bf(tile[rb + 0][cc]) | ((unsigned)f2bf(tile[rb + 1][cc]) << 16);
        w.y = (unsigned)f2bf(tile[rb + 2][cc]) | ((unsigned)f2bf(tile[rb + 3][cc]) << 16);
        w.z = (unsigned)f2bf(tile[rb + 4][cc]) | ((unsigned)f2bf(tile[rb + 5][cc]) << 16);
        w.w = (unsigned)f2bf(tile[rb + 6][cc]) | ((unsigned)f2bf(tile[rb + 7][cc]) << 16);
        *(uint4*)&out[((size_t)e * C + c0 + cc) * R + r0 + rb] = w;
    }
}

__global__ __launch_bounds__(256) void transpose_both_kernel(
    const float* __restrict__ W1, short* __restrict__ W1T,
    const float* __restrict__ W2, short* __restrict__ W2T)
{
    __shared__ float tile[64][65];
    int b = blockIdx.x;
    if (b < (FD / 64) * (HD / 64) * NE) {          // 8192 blocks for W1 [HD][FD]
        int e = b >> 10, r = b & 1023;
        transpose_tile<HD, FD>(W1, W1T, tile, r & 63, r >> 6, e);
    } else {                                       // 8192 blocks for W2 [FD][HD]
        b -= (FD / 64) * (HD / 64) * NE;
        int e = b >> 10, r = b & 1023;
        transpose_tile<FD, HD>(W2, W2T, tile, r & 15, r >> 4, e);
    }
}

// ---------------- gating: fp64 LN + logits + softmax + top-2 (one wave per token).
// x in fp32 regs ((double) conversion exact -> bit-identical math, no spill).
// exp() parallel on lanes 0..7; shuffle-gather is WAVE-UNIFORM (r19 bug: it was
// inside lane==0 -> divergent shfl read inactive lanes). Top-2 via static-indexed
// tournament (same strict->/first-tie semantics). Counters strided 128B.
__global__ __launch_bounds__(256) void gating_kernel(
    const float* __restrict__ x, const float* __restrict__ gn_g, const float* __restrict__ gn_b,
    const float* __restrict__ gate_w, const float* __restrict__ gate_b,
    int* __restrict__ topk_i, float* __restrict__ topk_w,
    int* __restrict__ rank, int* __restrict__ counts)
{
    const int wv = threadIdx.x >> 6, lane = threadIdx.x & 63;
    const int t = blockIdx.x * 4 + wv;
    const float* xr = x + (size_t)t * HD;

    float xs[16];
    #pragma unroll
    for (int i = 0; i < 16; ++i) xs[i] = xr[i * 64 + lane];

    double s = 0.0;
    #pragma unroll
    for (int i = 0; i < 16; ++i) s += (double)xs[i];
    #pragma unroll
    for (int o = 32; o > 0; o >>= 1) s += __shfl_xor(s, o, 64);
    const double mean = s * (1.0 / HD);
    double ss = 0.0;
    #pragma unroll
    for (int i = 0; i < 16; ++i) { double d = (double)xs[i] - mean; ss += d * d; }
    #pragma unroll
    for (int o = 32; o > 0; o >>= 1) ss += __shfl_xor(ss, o, 64);
    const double inv = 1.0 / sqrt(ss * (1.0 / HD) + 1e-5);

    double ac[NE];
    #pragma unroll
    for (int e = 0; e < NE; ++e) ac[e] = 0.0;
    #pragma unroll
    for (int i = 0; i < 16; ++i) {
        int h = i * 64 + lane;
        double ln = ((double)xs[i] - mean) * inv * (double)gn_g[h] + (double)gn_b[h];
        #pragma unroll
        for (int e = 0; e < NE; ++e) ac[e] += ln * (double)gate_w[h * NE + e];
    }
    #pragma unroll
    for (int e = 0; e < NE; ++e) {
        #pragma unroll
        for (int o = 32; o > 0; o >>= 1) ac[e] += __shfl_xor(ac[e], o, 64);
    }

    // lanes 0..7 (replicated in each 8-lane group): expert la computes its exp
    const int la = lane & 7;
    double lg = ac[0];
    #pragma unroll
    for (int e = 1; e < NE; ++e) if (la == e) lg = ac[e];
    lg += (double)gate_b[la];
    double mx = lg;
    #pragma unroll
    for (int o = 4; o > 0; o >>= 1) {
        double v = __shfl_xor(mx, o, 64);
        mx = v > mx ? v : mx;
    }
    double pe = exp(lg - mx);
    double ps = pe;
    #pragma unroll
    for (int o = 4; o > 0; o >>= 1) ps += __shfl_xor(ps, o, 64);
    pe /= ps;

    // WAVE-UNIFORM gather of the 8 probabilities (all lanes active)
    double p0 = __shfl(pe, 0, 64), p1 = __shfl(pe, 1, 64);
    double p2 = __shfl(pe, 2, 64), p3 = __shfl(pe, 3, 64);
    double p4 = __shfl(pe, 4, 64), p5 = __shfl(pe, 5, 64);
    double p6 = __shfl(pe, 6, 64), p7 = __shfl(pe, 7, 64);

    if (lane == 0) {
        // top-1: strict > keeps first (jax tie rule); static indexing only
        double v0 = p0; int i0 = 0;
        if (p1 > v0) { v0 = p1; i0 = 1; }
        if (p2 > v0) { v0 = p2; i0 = 2; }
        if (p3 > v0) { v0 = p3; i0 = 3; }
        if (p4 > v0) { v0 = p4; i0 = 4; }
        if (p5 > v0) { v0 = p5; i0 = 5; }
        if (p6 > v0) { v0 = p6; i0 = 6; }
        if (p7 > v0) { v0 = p7; i0 = 7; }
        // top-2: argmax over e != i0, strict >, first-tie
        double v1 = -1.0; int i1 = 0;
        if (i0 != 0 && p0 > v1) { v1 = p0; i1 = 0; }
        if (i0 != 1 && p1 > v1) { v1 = p1; i1 = 1; }
        if (i0 != 2 && p2 > v1) { v1 = p2; i1 = 2; }
        if (i0 != 3 && p3 > v1) { v1 = p3; i1 = 3; }
        if (i0 != 4 && p4 > v1) { v1 = p4; i1 = 4; }
        if (i0 != 5 && p5 > v1) { v1 = p5; i1 = 5; }
        if (i0 != 6 && p6 > v1) { v1 = p6; i1 = 6; }
        if (i0 != 7 && p7 > v1) { v1 = p7; i1 = 7; }
        double den = v0 + v1 + 1e-9;
        topk_i[t * 2] = i0; topk_i[t * 2 + 1] = i1;
        topk_w[t * 2] = (float)(v0 / den);
        topk_w[t * 2 + 1] = (float)(v1 / den);
        rank[t * 2]     = atomicAdd(&counts[i0 * CNTS], 1);
        rank[t * 2 + 1] = atomicAdd(&counts[i1 * CNTS], 1);
    }
}

// ---------------- gather x rows (fp32) -> Xg (bf16, grouped order); 8 pairs/block.
// offs computed inline from strided counts; writes inv_row for ln_combine.
__global__ __launch_bounds__(256) void gather_kernel(
    const float* __restrict__ x, const int* __restrict__ topk_i,
    const int* __restrict__ rank, const int* __restrict__ counts,
    int* __restrict__ inv_row, short* __restrict__ Xg)
{
    const int tid = threadIdx.x;
    int offv[NE];
    {
        int s = 0;
        #pragma unroll
        for (int k = 0; k < NE; ++k) { offv[k] = s; s += counts[k * CNTS]; }
    }
    #pragma unroll
    for (int i = 0; i < 8; ++i) {
        int p = blockIdx.x * 8 + i;
        int e = topk_i[p];
        int dst = offv[e] + rank[p];
        if (tid == 0) inv_row[p] = dst;
        int t = p >> 1;
        float4 v = *(const float4*)&x[(size_t)t * HD + tid * 4];
        unsigned w0 = (unsigned)f2bf(v.x) | ((unsigned)f2bf(v.y) << 16);
        unsigned w1 = (unsigned)f2bf(v.z) | ((unsigned)f2bf(v.w) << 16);
        *(uint2*)&Xg[(size_t)dst * HD + tid * 4] = make_uint2(w0, w1);
    }
}

// counted-vmcnt boundary: allow N loads (per wave) to stay in flight, then barrier.
#define WAITB(n) do {                                                   \
    asm volatile("s_waitcnt vmcnt(" #n ")" ::: "memory");               \
    __builtin_amdgcn_s_barrier();                                       \
    __builtin_amdgcn_sched_barrier(0);                                  \
} while (0)

#define GLOAD(srcp, dstp) __builtin_amdgcn_global_load_lds(                         \
        (const __attribute__((address_space(1))) unsigned*)(srcp),                  \
        (__attribute__((address_space(3))) unsigned*)(dstp), 16, 0, 0)

// ---------------- grouped GEMM (r13 structure), LDS-staged bf16 C epilogue.
// offs/ts computed inline from strided counts (prefix over 8).
// EPI==1: +bias, gelu -> bf16 Hb ; EPI==2: +bias -> bf16 Op (both grouped rows)
template<int KDIM, int NDIM, int EPI>
__global__ __launch_bounds__(512, 4) void gemm_kernel(
    const short* __restrict__ A, const short* __restrict__ BT,
    const float* __restrict__ bias, short* __restrict__ outp,
    const int* __restrict__ counts)
{
    // bijective XCD swizzle (nwg % 8 == 0: 16*136=2176, 4*136=544)
    const int nwg = gridDim.x * gridDim.y;
    const int orig = blockIdx.y * gridDim.x + blockIdx.x;
    const int v = (orig & 7) * (nwg >> 3) + (orig >> 3);
    const int bx = v % gridDim.x;             // col tile
    const int j = v / gridDim.x;              // global row tile

    // inline offs/ts prefix over strided counts
    int e = -1, rowbase = 0, rt = 0, cnt = 0;
    {
        int s = 0, t = 0;
        #pragma unroll
        for (int k = 0; k < NE; ++k) {
            int c = counts[k * CNTS];
            int nt = (c + BM - 1) >> 7;       // BM = 128
            if (e < 0 && j >= t && j < t + nt) {
                e = k; rt = j - t; rowbase = s + rt * BM; cnt = c;
            }
            s += c; t += nt;
        }
    }
    if (e < 0) return;                        // inactive tail block (block-uniform)

    const int colbase = bx * BN;
    const int tid = threadIdx.x;

    // 72 KB shared pool: K-loop = As(24KB) + Bs(48KB); epilogue reuses as C staging
    __shared__ __align__(16) short Smem[3 * BM * BK + 3 * BN * BK];
    short* As = Smem;
    short* Bs = Smem + 3 * BM * BK;

    const int lane = tid & 63;
    const int wv = tid >> 6;                  // 8 waves: 2 M-groups x 4 N-groups
    const int wr = (wv >> 2) * 64, wc = (wv & 3) * 64;
    const int l15 = lane & 15, l4 = lane >> 4;

    // staging: A = 4096 shorts (1 granule/thread), B = 8192 shorts (2 granules/thread)
    const int se0 = tid * 8;                  // LDS short index, rows 0..127
    const int sr0 = se0 >> 5;                 // staging row
    const int sg0 = (se0 >> 3) & 3;           // physical 16B granule within row
    const int sr1 = sr0 + 128;                // B pass 1 rows 128..255
    // pre-swizzled global k-offset: phys granule g holds global granule g^((r>>1)&3)
    const int sk0 = ((sg0 ^ ((sr0 >> 1) & 3)) << 3);
    const int sk1 = ((sg0 ^ ((sr1 >> 1) & 3)) << 3);

    // ds_read offsets: logical granule l4 of row r at phys g = l4^((r>>1)&3)
    int aoff[4], boff[4];
    #pragma unroll
    for (int m = 0; m < 4; ++m) {
        int r = wr + m * 16 + l15;
        aoff[m] = r * BK + ((l4 ^ ((r >> 1) & 3)) << 3);
    }
    #pragma unroll
    for (int n = 0; n < 4; ++n) {
        int r = wc + n * 16 + l15;
        boff[n] = r * BK + ((l4 ^ ((r >> 1) & 3)) << 3);
    }

    const size_t bbase = (size_t)e * NDIM + colbase;

#define STAGE(sl, k0) do {                                                                \
        short* asl = &As[(sl) * (BM * BK)];                                               \
        short* bsl = &Bs[(sl) * (BN * BK)];                                               \
        const short* a0s = A + (size_t)(rowbase + sr0) * KDIM + (k0) + sk0;               \
        GLOAD(a0s, &asl[se0]);                                                            \
        const short* b0s = BT + (bbase + sr0) * KDIM + (k0) + sk0;                        \
        GLOAD(b0s, &bsl[se0]);                                                            \
        const short* b1s = BT + (bbase + sr1) * KDIM + (k0) + sk1;                        \
        GLOAD(b1s, &bsl[se0 + 4096]);                                                     \
    } while (0)

    constexpr int NT = KDIM / BK;

    // prologue: stage tiles 0 and 1; wait tile 0 (allow tile 1's 3 loads in flight)
    STAGE(0, 0);
    STAGE(1, BK);
    WAITB(3);

    f32x4 acc[4][4];
    #pragma unroll
    for (int m = 0; m < 4; ++m)
        #pragma unroll
        for (int n = 0; n < 4; ++n)
            acc[m][n] = (f32x4){0.f, 0.f, 0.f, 0.f};

    for (int t = 0; t < NT; ++t) {
        if (t + 2 < NT) STAGE((t + 2) % 3, (t + 2) * BK);   // 2-K-tile prefetch

        const short* asl = &As[(t % 3) * (BM * BK)];
        const short* bsl = &Bs[(t % 3) * (BN * BK)];
        bf16x8 a[4], b[4];
        #pragma unroll
        for (int m = 0; m < 4; ++m)
            a[m] = *(const bf16x8*)&asl[aoff[m]];
        #pragma unroll
        for (int n = 0; n < 4; ++n)
            b[n] = *(const bf16x8*)&bsl[boff[n]];

        __builtin_amdgcn_s_setprio(1);
        #pragma unroll
        for (int m = 0; m < 4; ++m)
            #pragma unroll
            for (int n = 0; n < 4; ++n)
                acc[m][n] = __builtin_amdgcn_mfma_f32_16x16x32_bf16(a[m], b[n], acc[m][n], 0, 0, 0);
        __builtin_amdgcn_s_setprio(0);

        if (t < NT - 1) {
            if (t == NT - 2) WAITB(0); else WAITB(3);
        }
    }
#undef STAGE

    const int rmax = cnt - rt * BM;   // valid rows in this tile (tail tiles < BM)

    __syncthreads();              // all waves done reading As/Bs -> reuse as C staging
    short* Cs = Smem;             // [128][CSTR] shorts
    #pragma unroll
    for (int n = 0; n < 4; ++n) {
        int col = wc + n * 16 + l15;
        float bv = bias[e * NDIM + colbase + col];
        #pragma unroll
        for (int m = 0; m < 4; ++m) {
            int r0l = wr + m * 16 + l4 * 4;
            #pragma unroll
            for (int r = 0; r < 4; ++r) {
                float vv = acc[m][n][r] + bv;
                if (EPI == 1)
                    vv = 0.5f * vv * (1.0f + erff(vv * 0.70710678118654752f));
                Cs[(r0l + r) * CSTR + col] = (short)f2bf(vv);
            }
        }
    }
    __syncthreads();
    // copy out: 8 iters x 512 threads x 16B; row = i*16 + (tid>>5), col = (tid&31)*8
    const int crow0 = tid >> 5, ccol = (tid & 31) * 8;
    #pragma unroll
    for (int i = 0; i < 8; ++i) {
        int row = i * 16 + crow0;
        if (row < rmax) {
            const short* src = &Cs[row * CSTR + ccol];
            *(uint4*)&outp[(size_t)(rowbase + row) * NDIM + colbase + ccol] =
                *(const uint4*)src;
        }
    }
}

// ---------------- residual + LN + weighted top-k combine; one WAVE per token,
// shuffle-only reductions; Op is bf16 grouped rows.
__global__ __launch_bounds__(256) void ln_combine_kernel(
    const short* __restrict__ Op, const float* __restrict__ x,
    const int* __restrict__ topk_i, const float* __restrict__ topk_w,
    const int* __restrict__ inv_row,
    const float* __restrict__ ln_g, const float* __restrict__ ln_b,
    float* __restrict__ y)
{
    const int wvi = threadIdx.x >> 6, lane = threadIdx.x & 63;
    const int t = blockIdx.x * 4 + wvi;

    float4 xv[4];
    #pragma unroll
    for (int i = 0; i < 4; ++i)
        xv[i] = *(const float4*)&x[(size_t)t * HD + (lane + i * 64) * 4];

    float a[16];
    #pragma unroll
    for (int i = 0; i < 16; ++i) a[i] = 0.f;

    #pragma unroll
    for (int k = 0; k < TOPK; ++k) {
        const int e = topk_i[t * 2 + k];
        const float w = topk_w[t * 2 + k];
        const int grow = inv_row[t * 2 + k];

        float vbuf[16];
        float s = 0.f;
        #pragma unroll
        for (int i = 0; i < 4; ++i) {
            uint2 ov = *(const uint2*)&Op[(size_t)grow * HD + (lane + i * 64) * 4];
            float v0 = bf2f_lo(ov.x) + xv[i].x;
            float v1 = bf2f_hi(ov.x) + xv[i].y;
            float v2 = bf2f_lo(ov.y) + xv[i].z;
            float v3 = bf2f_hi(ov.y) + xv[i].w;
            vbuf[i * 4 + 0] = v0; vbuf[i * 4 + 1] = v1;
            vbuf[i * 4 + 2] = v2; vbuf[i * 4 + 3] = v3;
            s += (v0 + v1) + (v2 + v3);
        }
        #pragma unroll
        for (int o = 32; o > 0; o >>= 1) s += __shfl_xor(s, o, 64);
        const float m = s * (1.0f / HD);
        float ssq = 0.f;
        #pragma unroll
        for (int i = 0; i < 16; ++i) { float d = vbuf[i] - m; vbuf[i] = d; ssq += d * d; }
        #pragma unroll
        for (int o = 32; o > 0; o >>= 1) ssq += __shfl_xor(ssq, o, 64);
        const float inv = 1.0f / sqrtf(ssq * (1.0f / HD) + 1e-5f);

        #pragma unroll
        for (int i = 0; i < 4; ++i) {
            int base = e * HD + (lane + i * 64) * 4;
            const float4 g = *(const float4*)&ln_g[base];
            const float4 bb = *(const float4*)&ln_b[base];
            a[i * 4 + 0] += w * (vbuf[i * 4 + 0] * inv * g.x + bb.x);
            a[i * 4 + 1] += w * (vbuf[i * 4 + 1] * inv * g.y + bb.y);
            a[i * 4 + 2] += w * (vbuf[i * 4 + 2] * inv * g.z + bb.z);
            a[i * 4 + 3] += w * (vbuf[i * 4 + 3] * inv * g.w + bb.w);
        }
    }
    #pragma unroll
    for (int i = 0; i < 4; ++i)
        *(float4*)&y[(size_t)t * HD + (lane + i * 64) * 4] =
            make_float4(a[i * 4 + 0], a[i * 4 + 1], a[i * 4 + 2], a[i * 4 + 3]);
}

__global__ void zero_out_kernel(float* __restrict__ y, int n)
{
    int i = blockIdx.x * 256 + threadIdx.x;
    if (i < n) y[i] = 0.f;
}

extern "C" void kernel_launch(void* const* d_in, const int* in_sizes, int n_in,
                              void* d_out, int out_size, void* d_ws, size_t ws_size,
                              hipStream_t stream)
{
    const float* x      = (const float*)d_in[0];
    const float* W1     = (const float*)d_in[1];
    const float* b1     = (const float*)d_in[2];
    const float* W2     = (const float*)d_in[3];
    const float* b2     = (const float*)d_in[4];
    const float* ln_g   = (const float*)d_in[5];
    const float* ln_b   = (const float*)d_in[6];
    const float* gn_g   = (const float*)d_in[7];
    const float* gn_b   = (const float*)d_in[8];
    const float* gate_w = (const float*)d_in[9];
    const float* gate_b = (const float*)d_in[10];
    float* y = (float*)d_out;

    char* ws = (char*)d_ws;
    size_t off = 0;
    auto take = [&](size_t b) -> char* {
        char* p = ws + off;
        off = (off + b + 255) & ~(size_t)255;
        return p;
    };
    short* W1T     = (short*)take((size_t)NE * FD * HD * 2);       // [E][F][H] bf16
    short* W2T     = (short*)take((size_t)NE * HD * FD * 2);       // [E][H][F] bf16
    short* Xg      = (short*)take((size_t)(NPAIR + PADR) * HD * 2);
    short* Hb      = (short*)take((size_t)(NPAIR + PADR) * FD * 2);
    short* Op      = (short*)take((size_t)(NPAIR + PADR) * HD * 2);// bf16 grouped rows
    int*   topk_i  = (int*)take(NPAIR * 4);
    float* topk_w  = (float*)take(NPAIR * 4);
    int*   rank    = (int*)take(NPAIR * 4);
    int*   cnts    = (int*)take(NE * CNTS * 4);   // strided counters (128B apart)
    int*   inv_row = (int*)take((size_t)NPAIR * 4);

    if (ws_size < off) {   // workspace too small: emit zeros so failure mode is diagnosable
        zero_out_kernel<<<(out_size + 255) / 256, 256, 0, stream>>>(y, out_size);
        return;
    }

    hipMemsetAsync(cnts, 0, NE * CNTS * 4, stream);

    transpose_both_kernel<<<2 * (FD / 64) * (HD / 64) * NE, 256, 0, stream>>>(W1, W1T, W2, W2T);

    gating_kernel<<<TOK / 4, 256, 0, stream>>>(x, gn_g, gn_b, gate_w, gate_b,
                                               topk_i, topk_w, rank, cnts);
    gather_kernel<<<NPAIR / 8, 256, 0, stream>>>(x, topk_i, rank, cnts, inv_row, Xg);

    // Flat-tile balanced grouped GEMMs (r13 config, LDS-staged bf16 epilogues,
    // inline offs/ts from strided counts).
    gemm_kernel<HD, FD, 1><<<dim3(FD / BN, TMAX), 512, 0, stream>>>(
        Xg, W1T, b1, Hb, cnts);
    gemm_kernel<FD, HD, 2><<<dim3(HD / BN, TMAX), 512, 0, stream>>>(
        Hb, W2T, b2, Op, cnts);

    ln_combine_kernel<<<TOK / 4, 256, 0, stream>>>(Op, x, topk_i, topk_w, inv_row, ln_g, ln_b, y);
}

// Round 21
// 534.536 us; speedup vs baseline: 2.3798x; 1.0370x over previous
//
#include <hip/hip_runtime.h>
#include <hip/hip_bf16.h>

#define TOK   8192      // B*S
#define HD    1024      // H
#define FD    4096      // F
#define NE    8         // E
#define TOPK  2
#define NPAIR (TOK*TOPK)   // 16384, fixed
#define PADR  128          // row padding for tile overrun
#define BM    128
#define BN    256
#define BK    32
#define TMAX  (NPAIR/BM + NE)   // 136 grid rows; nwg stays %8==0
#define CSTR  276               // C-staging LDS row stride (shorts)
#define CNTS  32                // counter stride in ints (128 B -> one L2 line each)
#define TBLK  (2 * (FD / 64) * (HD / 64) * NE)   // 16384 transpose blocks

typedef short bf16x8 __attribute__((ext_vector_type(8)));
typedef float f32x4  __attribute__((ext_vector_type(4)));

__device__ inline unsigned short f2bf(float f) {
    unsigned u = __float_as_uint(f);
    unsigned r = (u + 0x7fffu + ((u >> 16) & 1u)) >> 16;
    return (unsigned short)r;
}
__device__ inline float bf2f_lo(unsigned u) { return __uint_as_float((u & 0xffffu) << 16); }
__device__ inline float bf2f_hi(unsigned u) { return __uint_as_float(u & 0xffff0000u); }

// ---------------- transpose tile helper (fp32 in [E][R][C] -> bf16 out [E][C][R])
template<int R, int C>
__device__ inline void transpose_tile(const float* __restrict__ in, short* __restrict__ out,
                                      float (*tile)[65], int cx, int ry, int e)
{
    const int tid = threadIdx.x;
    const int c0 = cx * 64, r0 = ry * 64;
    #pragma unroll
    for (int i = 0; i < 4; ++i) {
        int idx = i * 1024 + tid * 4;
        int rr = idx >> 6, cc = idx & 63;
        float4 v = *(const float4*)&in[((size_t)e * R + r0 + rr) * C + c0 + cc];
        tile[rr][cc] = v.x; tile[rr][cc + 1] = v.y;
        tile[rr][cc + 2] = v.z; tile[rr][cc + 3] = v.w;
    }
    __syncthreads();
    #pragma unroll
    for (int i = 0; i < 2; ++i) {
        int idx = i * 256 + tid;
        int cc = idx >> 3, rb = (idx & 7) * 8;
        uint4 w;
        w.x = (unsigned)f2bf(tile[rb + 0][cc]) | ((unsigned)f2bf(tile[rb + 1][cc]) << 16);
        w.y = (unsigned)f2bf(tile[rb + 2][cc]) | ((unsigned)f2bf(tile[rb + 3][cc]) << 16);
        w.z = (unsigned)f2bf(tile[rb + 4][cc]) | ((unsigned)f2bf(tile[rb + 5][cc]) << 16);
        w.w = (unsigned)f2bf(tile[rb + 6][cc]) | ((unsigned)f2bf(tile[rb + 7][cc]) << 16);
        *(uint4*)&out[((size_t)e * C + c0 + cc) * R + r0 + rb] = w;
    }
}

// ---------------- fused: weight transposes (HBM-bound) + gating (fp64-VALU-bound).
// Complementary pipes -> co-resident blocks overlap; one launch instead of two.
// Gating math identical to r20 (verified): fp32 x regs, exact (double) promote,
// parallel exp on lanes 0..7, WAVE-UNIFORM shuffle gather, static top-2 tournament.
__global__ __launch_bounds__(256) void prep_kernel(
    const float* __restrict__ W1, short* __restrict__ W1T,
    const float* __restrict__ W2, short* __restrict__ W2T,
    const float* __restrict__ x, const float* __restrict__ gn_g, const float* __restrict__ gn_b,
    const float* __restrict__ gate_w, const float* __restrict__ gate_b,
    int* __restrict__ topk_i, float* __restrict__ topk_w,
    int* __restrict__ rank, int* __restrict__ counts)
{
    __shared__ float tile[64][65];
    int b = blockIdx.x;
    if (b < TBLK / 2) {                            // W1 [HD][FD] -> [FD][HD]
        int e = b >> 10, r = b & 1023;
        transpose_tile<HD, FD>(W1, W1T, tile, r & 63, r >> 6, e);
        return;
    }
    b -= TBLK / 2;
    if (b < TBLK / 2) {                            // W2 [FD][HD] -> [HD][FD]
        int e = b >> 10, r = b & 1023;
        transpose_tile<FD, HD>(W2, W2T, tile, r & 15, r >> 4, e);
        return;
    }
    b -= TBLK / 2;                                 // gating: 4 tokens/block

    const int wv = threadIdx.x >> 6, lane = threadIdx.x & 63;
    const int t = b * 4 + wv;
    const float* xr = x + (size_t)t * HD;

    float xs[16];
    #pragma unroll
    for (int i = 0; i < 16; ++i) xs[i] = xr[i * 64 + lane];

    double s = 0.0;
    #pragma unroll
    for (int i = 0; i < 16; ++i) s += (double)xs[i];
    #pragma unroll
    for (int o = 32; o > 0; o >>= 1) s += __shfl_xor(s, o, 64);
    const double mean = s * (1.0 / HD);
    double ss = 0.0;
    #pragma unroll
    for (int i = 0; i < 16; ++i) { double d = (double)xs[i] - mean; ss += d * d; }
    #pragma unroll
    for (int o = 32; o > 0; o >>= 1) ss += __shfl_xor(ss, o, 64);
    const double inv = 1.0 / sqrt(ss * (1.0 / HD) + 1e-5);

    double ac[NE];
    #pragma unroll
    for (int e = 0; e < NE; ++e) ac[e] = 0.0;
    #pragma unroll
    for (int i = 0; i < 16; ++i) {
        int h = i * 64 + lane;
        double ln = ((double)xs[i] - mean) * inv * (double)gn_g[h] + (double)gn_b[h];
        #pragma unroll
        for (int e = 0; e < NE; ++e) ac[e] += ln * (double)gate_w[h * NE + e];
    }
    #pragma unroll
    for (int e = 0; e < NE; ++e) {
        #pragma unroll
        for (int o = 32; o > 0; o >>= 1) ac[e] += __shfl_xor(ac[e], o, 64);
    }

    const int la = lane & 7;
    double lg = ac[0];
    #pragma unroll
    for (int e = 1; e < NE; ++e) if (la == e) lg = ac[e];
    lg += (double)gate_b[la];
    double mx = lg;
    #pragma unroll
    for (int o = 4; o > 0; o >>= 1) {
        double v = __shfl_xor(mx, o, 64);
        mx = v > mx ? v : mx;
    }
    double pe = exp(lg - mx);
    double ps = pe;
    #pragma unroll
    for (int o = 4; o > 0; o >>= 1) ps += __shfl_xor(ps, o, 64);
    pe /= ps;

    // WAVE-UNIFORM gather of the 8 probabilities (all lanes active)
    double p0 = __shfl(pe, 0, 64), p1 = __shfl(pe, 1, 64);
    double p2 = __shfl(pe, 2, 64), p3 = __shfl(pe, 3, 64);
    double p4 = __shfl(pe, 4, 64), p5 = __shfl(pe, 5, 64);
    double p6 = __shfl(pe, 6, 64), p7 = __shfl(pe, 7, 64);

    if (lane == 0) {
        double v0 = p0; int i0 = 0;
        if (p1 > v0) { v0 = p1; i0 = 1; }
        if (p2 > v0) { v0 = p2; i0 = 2; }
        if (p3 > v0) { v0 = p3; i0 = 3; }
        if (p4 > v0) { v0 = p4; i0 = 4; }
        if (p5 > v0) { v0 = p5; i0 = 5; }
        if (p6 > v0) { v0 = p6; i0 = 6; }
        if (p7 > v0) { v0 = p7; i0 = 7; }
        double v1 = -1.0; int i1 = 0;
        if (i0 != 0 && p0 > v1) { v1 = p0; i1 = 0; }
        if (i0 != 1 && p1 > v1) { v1 = p1; i1 = 1; }
        if (i0 != 2 && p2 > v1) { v1 = p2; i1 = 2; }
        if (i0 != 3 && p3 > v1) { v1 = p3; i1 = 3; }
        if (i0 != 4 && p4 > v1) { v1 = p4; i1 = 4; }
        if (i0 != 5 && p5 > v1) { v1 = p5; i1 = 5; }
        if (i0 != 6 && p6 > v1) { v1 = p6; i1 = 6; }
        if (i0 != 7 && p7 > v1) { v1 = p7; i1 = 7; }
        double den = v0 + v1 + 1e-9;
        topk_i[t * 2] = i0; topk_i[t * 2 + 1] = i1;
        topk_w[t * 2] = (float)(v0 / den);
        topk_w[t * 2 + 1] = (float)(v1 / den);
        rank[t * 2]     = atomicAdd(&counts[i0 * CNTS], 1);
        rank[t * 2 + 1] = atomicAdd(&counts[i1 * CNTS], 1);
    }
}

// ---------------- gather x rows -> Xg (bf16, grouped); 4 TOKENS/block (x read once,
// both expert copies written). offs inline from strided counts; emits inv_row.
__global__ __launch_bounds__(256) void gather_kernel(
    const float* __restrict__ x, const int* __restrict__ topk_i,
    const int* __restrict__ rank, const int* __restrict__ counts,
    int* __restrict__ inv_row, short* __restrict__ Xg)
{
    const int tid = threadIdx.x;
    int offv[NE];
    {
        int s = 0;
        #pragma unroll
        for (int k = 0; k < NE; ++k) { offv[k] = s; s += counts[k * CNTS]; }
    }
    #pragma unroll
    for (int i = 0; i < 4; ++i) {
        int t = blockIdx.x * 4 + i;
        float4 v = *(const float4*)&x[(size_t)t * HD + tid * 4];
        unsigned w0 = (unsigned)f2bf(v.x) | ((unsigned)f2bf(v.y) << 16);
        unsigned w1 = (unsigned)f2bf(v.z) | ((unsigned)f2bf(v.w) << 16);
        uint2 pk = make_uint2(w0, w1);
        #pragma unroll
        for (int k = 0; k < 2; ++k) {
            int p = t * 2 + k;
            int dst = offv[topk_i[p]] + rank[p];
            if (tid == 0) inv_row[p] = dst;
            *(uint2*)&Xg[(size_t)dst * HD + tid * 4] = pk;
        }
    }
}

// counted-vmcnt boundary: allow N loads (per wave) to stay in flight, then barrier.
#define WAITB(n) do {                                                   \
    asm volatile("s_waitcnt vmcnt(" #n ")" ::: "memory");               \
    __builtin_amdgcn_s_barrier();                                       \
    __builtin_amdgcn_sched_barrier(0);                                  \
} while (0)

#define GLOAD(srcp, dstp) __builtin_amdgcn_global_load_lds(                         \
        (const __attribute__((address_space(1))) unsigned*)(srcp),                  \
        (__attribute__((address_space(3))) unsigned*)(dstp), 16, 0, 0)

// ---------------- grouped GEMM (r13 structure), LDS-staged bf16 C epilogue.
// offs/ts computed inline from strided counts (prefix over 8).
// EPI==1: +bias, gelu -> bf16 Hb ; EPI==2: +bias -> bf16 Op (both grouped rows)
template<int KDIM, int NDIM, int EPI>
__global__ __launch_bounds__(512, 4) void gemm_kernel(
    const short* __restrict__ A, const short* __restrict__ BT,
    const float* __restrict__ bias, short* __restrict__ outp,
    const int* __restrict__ counts)
{
    // bijective XCD swizzle (nwg % 8 == 0: 16*136=2176, 4*136=544)
    const int nwg = gridDim.x * gridDim.y;
    const int orig = blockIdx.y * gridDim.x + blockIdx.x;
    const int v = (orig & 7) * (nwg >> 3) + (orig >> 3);
    const int bx = v % gridDim.x;             // col tile
    const int j = v / gridDim.x;              // global row tile

    // inline offs/ts prefix over strided counts
    int e = -1, rowbase = 0, rt = 0, cnt = 0;
    {
        int s = 0, t = 0;
        #pragma unroll
        for (int k = 0; k < NE; ++k) {
            int c = counts[k * CNTS];
            int nt = (c + BM - 1) >> 7;       // BM = 128
            if (e < 0 && j >= t && j < t + nt) {
                e = k; rt = j - t; rowbase = s + rt * BM; cnt = c;
            }
            s += c; t += nt;
        }
    }
    if (e < 0) return;                        // inactive tail block (block-uniform)

    const int colbase = bx * BN;
    const int tid = threadIdx.x;

    // 72 KB shared pool: K-loop = As(24KB) + Bs(48KB); epilogue reuses as C staging
    __shared__ __align__(16) short Smem[3 * BM * BK + 3 * BN * BK];
    short* As = Smem;
    short* Bs = Smem + 3 * BM * BK;

    const int lane = tid & 63;
    const int wv = tid >> 6;                  // 8 waves: 2 M-groups x 4 N-groups
    const int wr = (wv >> 2) * 64, wc = (wv & 3) * 64;
    const int l15 = lane & 15, l4 = lane >> 4;

    // staging: A = 4096 shorts (1 granule/thread), B = 8192 shorts (2 granules/thread)
    const int se0 = tid * 8;                  // LDS short index, rows 0..127
    const int sr0 = se0 >> 5;                 // staging row
    const int sg0 = (se0 >> 3) & 3;           // physical 16B granule within row
    const int sr1 = sr0 + 128;                // B pass 1 rows 128..255
    // pre-swizzled global k-offset: phys granule g holds global granule g^((r>>1)&3)
    const int sk0 = ((sg0 ^ ((sr0 >> 1) & 3)) << 3);
    const int sk1 = ((sg0 ^ ((sr1 >> 1) & 3)) << 3);

    // ds_read offsets: logical granule l4 of row r at phys g = l4^((r>>1)&3)
    int aoff[4], boff[4];
    #pragma unroll
    for (int m = 0; m < 4; ++m) {
        int r = wr + m * 16 + l15;
        aoff[m] = r * BK + ((l4 ^ ((r >> 1) & 3)) << 3);
    }
    #pragma unroll
    for (int n = 0; n < 4; ++n) {
        int r = wc + n * 16 + l15;
        boff[n] = r * BK + ((l4 ^ ((r >> 1) & 3)) << 3);
    }

    const size_t bbase = (size_t)e * NDIM + colbase;

#define STAGE(sl, k0) do {                                                                \
        short* asl = &As[(sl) * (BM * BK)];                                               \
        short* bsl = &Bs[(sl) * (BN * BK)];                                               \
        const short* a0s = A + (size_t)(rowbase + sr0) * KDIM + (k0) + sk0;               \
        GLOAD(a0s, &asl[se0]);                                                            \
        const short* b0s = BT + (bbase + sr0) * KDIM + (k0) + sk0;                        \
        GLOAD(b0s, &bsl[se0]);                                                            \
        const short* b1s = BT + (bbase + sr1) * KDIM + (k0) + sk1;                        \
        GLOAD(b1s, &bsl[se0 + 4096]);                                                     \
    } while (0)

    constexpr int NT = KDIM / BK;

    // prologue: stage tiles 0 and 1; wait tile 0 (allow tile 1's 3 loads in flight)
    STAGE(0, 0);
    STAGE(1, BK);
    WAITB(3);

    f32x4 acc[4][4];
    #pragma unroll
    for (int m = 0; m < 4; ++m)
        #pragma unroll
        for (int n = 0; n < 4; ++n)
            acc[m][n] = (f32x4){0.f, 0.f, 0.f, 0.f};

    for (int t = 0; t < NT; ++t) {
        if (t + 2 < NT) STAGE((t + 2) % 3, (t + 2) * BK);   // 2-K-tile prefetch

        const short* asl = &As[(t % 3) * (BM * BK)];
        const short* bsl = &Bs[(t % 3) * (BN * BK)];
        bf16x8 a[4], b[4];
        #pragma unroll
        for (int m = 0; m < 4; ++m)
            a[m] = *(const bf16x8*)&asl[aoff[m]];
        #pragma unroll
        for (int n = 0; n < 4; ++n)
            b[n] = *(const bf16x8*)&bsl[boff[n]];

        __builtin_amdgcn_s_setprio(1);
        #pragma unroll
        for (int m = 0; m < 4; ++m)
            #pragma unroll
            for (int n = 0; n < 4; ++n)
                acc[m][n] = __builtin_amdgcn_mfma_f32_16x16x32_bf16(a[m], b[n], acc[m][n], 0, 0, 0);
        __builtin_amdgcn_s_setprio(0);

        if (t < NT - 1) {
            if (t == NT - 2) WAITB(0); else WAITB(3);
        }
    }
#undef STAGE

    const int rmax = cnt - rt * BM;   // valid rows in this tile (tail tiles < BM)

    __syncthreads();              // all waves done reading As/Bs -> reuse as C staging
    short* Cs = Smem;             // [128][CSTR] shorts
    #pragma unroll
    for (int n = 0; n < 4; ++n) {
        int col = wc + n * 16 + l15;
        float bv = bias[e * NDIM + colbase + col];
        #pragma unroll
        for (int m = 0; m < 4; ++m) {
            int r0l = wr + m * 16 + l4 * 4;
            #pragma unroll
            for (int r = 0; r < 4; ++r) {
                float vv = acc[m][n][r] + bv;
                if (EPI == 1)
                    vv = 0.5f * vv * (1.0f + erff(vv * 0.70710678118654752f));
                Cs[(r0l + r) * CSTR + col] = (short)f2bf(vv);
            }
        }
    }
    __syncthreads();
    // copy out: 8 iters x 512 threads x 16B; row = i*16 + (tid>>5), col = (tid&31)*8
    const int crow0 = tid >> 5, ccol = (tid & 31) * 8;
    #pragma unroll
    for (int i = 0; i < 8; ++i) {
        int row = i * 16 + crow0;
        if (row < rmax) {
            const short* src = &Cs[row * CSTR + ccol];
            *(uint4*)&outp[(size_t)(rowbase + row) * NDIM + colbase + ccol] =
                *(const uint4*)src;
        }
    }
}

// ---------------- residual + LN + weighted top-k combine; one WAVE per token,
// shuffle-only reductions; Op is bf16 grouped rows.
__global__ __launch_bounds__(256) void ln_combine_kernel(
    const short* __restrict__ Op, const float* __restrict__ x,
    const int* __restrict__ topk_i, const float* __restrict__ topk_w,
    const int* __restrict__ inv_row,
    const float* __restrict__ ln_g, const float* __restrict__ ln_b,
    float* __restrict__ y)
{
    const int wvi = threadIdx.x >> 6, lane = threadIdx.x & 63;
    const int t = blockIdx.x * 4 + wvi;

    float4 xv[4];
    #pragma unroll
    for (int i = 0; i < 4; ++i)
        xv[i] = *(const float4*)&x[(size_t)t * HD + (lane + i * 64) * 4];

    float a[16];
    #pragma unroll
    for (int i = 0; i < 16; ++i) a[i] = 0.f;

    #pragma unroll
    for (int k = 0; k < TOPK; ++k) {
        const int e = topk_i[t * 2 + k];
        const float w = topk_w[t * 2 + k];
        const int grow = inv_row[t * 2 + k];

        float vbuf[16];
        float s = 0.f;
        #pragma unroll
        for (int i = 0; i < 4; ++i) {
            uint2 ov = *(const uint2*)&Op[(size_t)grow * HD + (lane + i * 64) * 4];
            float v0 = bf2f_lo(ov.x) + xv[i].x;
            float v1 = bf2f_hi(ov.x) + xv[i].y;
            float v2 = bf2f_lo(ov.y) + xv[i].z;
            float v3 = bf2f_hi(ov.y) + xv[i].w;
            vbuf[i * 4 + 0] = v0; vbuf[i * 4 + 1] = v1;
            vbuf[i * 4 + 2] = v2; vbuf[i * 4 + 3] = v3;
            s += (v0 + v1) + (v2 + v3);
        }
        #pragma unroll
        for (int o = 32; o > 0; o >>= 1) s += __shfl_xor(s, o, 64);
        const float m = s * (1.0f / HD);
        float ssq = 0.f;
        #pragma unroll
        for (int i = 0; i < 16; ++i) { float d = vbuf[i] - m; vbuf[i] = d; ssq += d * d; }
        #pragma unroll
        for (int o = 32; o > 0; o >>= 1) ssq += __shfl_xor(ssq, o, 64);
        const float inv = 1.0f / sqrtf(ssq * (1.0f / HD) + 1e-5f);

        #pragma unroll
        for (int i = 0; i < 4; ++i) {
            int base = e * HD + (lane + i * 64) * 4;
            const float4 g = *(const float4*)&ln_g[base];
            const float4 bb = *(const float4*)&ln_b[base];
            a[i * 4 + 0] += w * (vbuf[i * 4 + 0] * inv * g.x + bb.x);
            a[i * 4 + 1] += w * (vbuf[i * 4 + 1] * inv * g.y + bb.y);
            a[i * 4 + 2] += w * (vbuf[i * 4 + 2] * inv * g.z + bb.z);
            a[i * 4 + 3] += w * (vbuf[i * 4 + 3] * inv * g.w + bb.w);
        }
    }
    #pragma unroll
    for (int i = 0; i < 4; ++i)
        *(float4*)&y[(size_t)t * HD + (lane + i * 64) * 4] =
            make_float4(a[i * 4 + 0], a[i * 4 + 1], a[i * 4 + 2], a[i * 4 + 3]);
}

__global__ void zero_out_kernel(float* __restrict__ y, int n)
{
    int i = blockIdx.x * 256 + threadIdx.x;
    if (i < n) y[i] = 0.f;
}

extern "C" void kernel_launch(void* const* d_in, const int* in_sizes, int n_in,
                              void* d_out, int out_size, void* d_ws, size_t ws_size,
                              hipStream_t stream)
{
    const float* x      = (const float*)d_in[0];
    const float* W1     = (const float*)d_in[1];
    const float* b1     = (const float*)d_in[2];
    const float* W2     = (const float*)d_in[3];
    const float* b2     = (const float*)d_in[4];
    const float* ln_g   = (const float*)d_in[5];
    const float* ln_b   = (const float*)d_in[6];
    const float* gn_g   = (const float*)d_in[7];
    const float* gn_b   = (const float*)d_in[8];
    const float* gate_w = (const float*)d_in[9];
    const float* gate_b = (const float*)d_in[10];
    float* y = (float*)d_out;

    char* ws = (char*)d_ws;
    size_t off = 0;
    auto take = [&](size_t b) -> char* {
        char* p = ws + off;
        off = (off + b + 255) & ~(size_t)255;
        return p;
    };
    short* W1T     = (short*)take((size_t)NE * FD * HD * 2);       // [E][F][H] bf16
    short* W2T     = (short*)take((size_t)NE * HD * FD * 2);       // [E][H][F] bf16
    short* Xg      = (short*)take((size_t)(NPAIR + PADR) * HD * 2);
    short* Hb      = (short*)take((size_t)(NPAIR + PADR) * FD * 2);
    short* Op      = (short*)take((size_t)(NPAIR + PADR) * HD * 2);// bf16 grouped rows
    int*   topk_i  = (int*)take(NPAIR * 4);
    float* topk_w  = (float*)take(NPAIR * 4);
    int*   rank    = (int*)take(NPAIR * 4);
    int*   cnts    = (int*)take(NE * CNTS * 4);   // strided counters (128B apart)
    int*   inv_row = (int*)take((size_t)NPAIR * 4);

    if (ws_size < off) {   // workspace too small: emit zeros so failure mode is diagnosable
        zero_out_kernel<<<(out_size + 255) / 256, 256, 0, stream>>>(y, out_size);
        return;
    }

    hipMemsetAsync(cnts, 0, NE * CNTS * 4, stream);

    // fused transposes + gating (one launch; complementary BW/VALU pipes overlap)
    prep_kernel<<<TBLK + TOK / 4, 256, 0, stream>>>(
        W1, W1T, W2, W2T, x, gn_g, gn_b, gate_w, gate_b, topk_i, topk_w, rank, cnts);

    gather_kernel<<<TOK / 4, 256, 0, stream>>>(x, topk_i, rank, cnts, inv_row, Xg);

    // Flat-tile balanced grouped GEMMs (r13 config, LDS-staged bf16 epilogues,
    // inline offs/ts from strided counts).
    gemm_kernel<HD, FD, 1><<<dim3(FD / BN, TMAX), 512, 0, stream>>>(
        Xg, W1T, b1, Hb, cnts);
    gemm_kernel<FD, HD, 2><<<dim3(HD / BN, TMAX), 512, 0, stream>>>(
        Hb, W2T, b2, Op, cnts);

    ln_combine_kernel<<<TOK / 4, 256, 0, stream>>>(Op, x, topk_i, topk_w, inv_row, ln_g, ln_b, y);
}